// Round 13
// baseline (1231.939 us; speedup 1.0000x reference)
//
#include <hip/hip_runtime.h>

typedef short short8 __attribute__((ext_vector_type(8)));
typedef float f4 __attribute__((ext_vector_type(4)));
typedef int i4 __attribute__((ext_vector_type(4)));
typedef _Float16 half8 __attribute__((ext_vector_type(8)));
typedef _Float16 h2 __attribute__((ext_vector_type(2)));

#define HD 256
#define ED 300
#define EP 320
#define TH 768
#define NS 1024
#define LW 64
#define SH 4.5f

#define BAR_LDS() do { asm volatile("s_waitcnt lgkmcnt(0)" ::: "memory"); \
                       __builtin_amdgcn_s_barrier(); } while (0)

__device__ __forceinline__ unsigned short f2bf(float f) {
    unsigned int u = __float_as_uint(f);
    u = (u + 0x7FFFu + ((u >> 16) & 1u)) >> 16;
    return (unsigned short)u;
}
__device__ __forceinline__ float bf2f(unsigned short s) {
    return __uint_as_float(((unsigned int)s) << 16);
}
__device__ __forceinline__ float sigm(float x) {
    return __builtin_amdgcn_rcpf(1.f + __expf(-x));
}
__device__ __forceinline__ float tanh_(float x) {
    x = fminf(fmaxf(x, -15.f), 15.f);
    return 1.f - 2.f * __builtin_amdgcn_rcpf(1.f + __expf(2.f * x));
}
__device__ __forceinline__ unsigned int pack_h2(float a, float b) {
    h2 p; p.x = (_Float16)a; p.y = (_Float16)b;
    return __builtin_bit_cast(unsigned int, p);
}

__device__ __forceinline__ void load8bf(const unsigned short* p, float* o) {
    uint4 a = *(const uint4*)p;
    o[0] = bf2f((unsigned short)(a.x & 0xffff)); o[1] = bf2f((unsigned short)(a.x >> 16));
    o[2] = bf2f((unsigned short)(a.y & 0xffff)); o[3] = bf2f((unsigned short)(a.y >> 16));
    o[4] = bf2f((unsigned short)(a.z & 0xffff)); o[5] = bf2f((unsigned short)(a.z >> 16));
    o[6] = bf2f((unsigned short)(a.w & 0xffff)); o[7] = bf2f((unsigned short)(a.w >> 16));
}
__device__ __forceinline__ void ubf4(uint2 a, float* o) {
    o[0] = bf2f((unsigned short)(a.x & 0xffff)); o[1] = bf2f((unsigned short)(a.x >> 16));
    o[2] = bf2f((unsigned short)(a.y & 0xffff)); o[3] = bf2f((unsigned short)(a.y >> 16));
}

// ---------------- prep: weight conversions, i8 quantization (ALL 768 Whh rows), Dq, topic ----------------
__global__ void k_prep(const float* __restrict__ W, const float* __restrict__ U,
                       const float* __restrict__ Wih, const float* __restrict__ Whh,
                       const float* __restrict__ q, const float* __restrict__ Dm,
                       const float* __restrict__ DT, const float* __restrict__ mlpW,
                       const float* __restrict__ mlpb,
                       const float* __restrict__ bih, const float* __restrict__ bhh,
                       unsigned short* __restrict__ Wb, _Float16* __restrict__ Uh,
                       _Float16* __restrict__ Wihh,
                       signed char* __restrict__ Wq, float* __restrict__ rowscale,
                       float* __restrict__ bias2,
                       float* __restrict__ Dq, float* __restrict__ tv) {
    __shared__ float smax[4];
    int bid = blockIdx.x, tid = threadIdx.x;
    if (bid < 768) {
        int r = bid;
        for (int j = tid; j < EP; j += 256)
            Wb[r * EP + j] = (j < ED) ? f2bf(W[r * ED + j]) : (unsigned short)0;
        float whv = Whh[r * HD + tid];
        for (int j = tid; j < HD; j += 256) {
            Uh[r * HD + j] = (_Float16)U[r * HD + j];
            Wihh[r * HD + j] = (_Float16)Wih[r * HD + j];
        }
        // per-row i8 quantization of ALL Whh rows
        float v = fabsf(whv);
        for (int o = 32; o; o >>= 1) v = fmaxf(v, __shfl_xor(v, o));
        if ((tid & 63) == 0) smax[tid >> 6] = v;
        __syncthreads();
        float am = fmaxf(fmaxf(smax[0], smax[1]), fmaxf(smax[2], smax[3]));
        float inv = (am > 0.f) ? 127.f / am : 0.f;
        int qi = (int)rintf(whv * inv);
        qi = max(-127, min(127, qi));
        Wq[r * HD + tid] = (signed char)qi;
        if (tid == 0) rowscale[r] = (am / 127.f) * (SH / 127.f);
    } else if (bid < 798) {
        int idx = bid - 768;
        int d = idx / 3, part = idx - d * 3;
        int n = part * 256 + tid;
        float s = 0.f;
        for (int h = 0; h < HD; ++h) s += Dm[n * HD + h] * q[d * HD + h];
        Dq[d * TH + n] = s;
    } else {
        if (tid < HD) {
            float s = 0.f;
            for (int k = 0; k < 100; ++k) s += mlpW[tid * 100 + k] * DT[k];
            tv[tid] = tanh_(s + mlpb[tid]);
        }
        for (int r = tid; r < TH; r += 256)
            bias2[r] = bih[r] + ((r < 512) ? bhh[r] : 0.f);
    }
}

// ---------------- phase B v5: v4 occupancy + v3 coalesced writes (aliased LDS, zero extra cost) ----------------
// r12 counters: v4's direct uint2 stores caused 6.5x write amplification (WRITE 98->637MB,
// FETCH +250MB from write-allocate line fills) -> BW-bound at 3.3TB/s on self-inflicted traffic.
// v5: one 24.8KB shared buffer aliased as (a) xbf gather stage during the K-loop, then (b) tbuf
// write-staging tile in the epilogue (xbf dead after K-loop; barrier between). Keeps v4's
// 4-blocks/CU occupancy AND v3's full-line uint4 stores.
#define XP 328
__launch_bounds__(256, 4)
__global__ void k_phaseB(const int* __restrict__ sIdx, const int* __restrict__ depT,
                         const float* __restrict__ emb, const unsigned short* __restrict__ Wb,
                         const float* __restrict__ Dq, const float* __restrict__ bias,
                         unsigned short* __restrict__ pre) {
    __shared__ __align__(16) unsigned short sbuf[16 * 776]; // 24832B; xbf needs 20992B
    unsigned short* xbf = sbuf;
    unsigned short* tbuf = sbuf;
    int tid = threadIdx.x;
    int c0 = blockIdx.x * 32;

    // stage 32 gathered x rows as bf16 (float4 loads; emb rows are 1200B = 75x16B aligned)
    for (int i = tid; i < 32 * 80; i += 256) {
        int row = i / 80, c4 = i - row * 80;
        unsigned int lo = 0, hi = 0;
        if (c4 < 75) {
            int idx = sIdx[c0 + row];
            float4 v = *(const float4*)(emb + (long)idx * ED + c4 * 4);
            lo = (unsigned int)f2bf(v.x) | ((unsigned int)f2bf(v.y) << 16);
            hi = (unsigned int)f2bf(v.z) | ((unsigned int)f2bf(v.w) << 16);
        }
        uint2 pv; pv.x = lo; pv.y = hi;
        *(uint2*)&xbf[row * XP + c4 * 4] = pv;
    }
    __syncthreads();

    int lane = tid & 63;
    int w = tid >> 6;
    int quad = lane >> 4, l16 = lane & 15;

    f4 acc[2][12];
#pragma unroll
    for (int cs = 0; cs < 2; ++cs)
#pragma unroll
        for (int ms = 0; ms < 12; ++ms) acc[cs][ms] = (f4){0.f, 0.f, 0.f, 0.f};

    const unsigned short* wbase = Wb + (w * 192 + l16) * EP;

#pragma unroll
    for (int kt = 0; kt < 10; ++kt) {
        int k0 = kt * 32 + quad * 8;
        short8 bf0 = *(const short8*)&xbf[l16 * XP + k0];
        short8 bf1 = *(const short8*)&xbf[(16 + l16) * XP + k0];
#pragma unroll
        for (int ms = 0; ms < 12; ++ms) {
            short8 af = *(const short8*)(wbase + ms * 16 * EP + k0);
            acc[0][ms] = __builtin_amdgcn_mfma_f32_16x16x32_bf16(af, bf0, acc[0][ms], 0, 0, 0);
            acc[1][ms] = __builtin_amdgcn_mfma_f32_16x16x32_bf16(af, bf1, acc[1][ms], 0, 0, 0);
        }
    }
    __syncthreads();   // xbf dead from here; sbuf becomes tbuf

#pragma unroll
    for (int cs = 0; cs < 2; ++cs) {
        int xr = c0 + cs * 16 + l16;
        int l = xr & 63, s = xr >> 6;
        int dep = (l == 63) ? 9 : depT[s * 63 + l];
        const float* dqrow = Dq + dep * TH;
#pragma unroll
        for (int ms = 0; ms < 12; ++ms) {
            int ncol = w * 192 + ms * 16 + quad * 4;
            f4 dq4 = *(const f4*)&dqrow[ncol];    // L2-resident (30KB table)
            f4 b4 = *(const f4*)&bias[ncol];
            unsigned int lo = (unsigned int)f2bf(acc[cs][ms][0] + dq4[0] + b4[0]) |
                              ((unsigned int)f2bf(acc[cs][ms][1] + dq4[1] + b4[1]) << 16);
            unsigned int hi = (unsigned int)f2bf(acc[cs][ms][2] + dq4[2] + b4[2]) |
                              ((unsigned int)f2bf(acc[cs][ms][3] + dq4[3] + b4[3]) << 16);
            uint2 v; v.x = lo; v.y = hi;
            *(uint2*)&tbuf[l16 * 776 + ncol] = v;
        }
        __syncthreads();
        // coalesced row-major store: 16 rows x 96 uint4 chunks = 1536 / 256 thr = 6 iters
        for (int it = 0; it < 6; ++it) {
            int flat = it * 256 + tid;
            int row = flat / 96;
            int ch = flat - row * 96;
            uint4 v = *(const uint4*)&tbuf[row * 776 + ch * 8];
            *(uint4*)(pre + (long)(c0 + cs * 16 + row) * TH + ch * 8) = v;
        }
        __syncthreads();
    }
}

// ---------------- phase C v2: 4 sentences/block x 256 blocks (full-chip), raw LDS barriers ----------------
#define NSB 4
__global__ void __launch_bounds__(768) k_phaseC(
                         const unsigned short* __restrict__ pre,
                         const _Float16* __restrict__ Uh,
                         const _Float16* __restrict__ Wihh,
                         const float* __restrict__ bias2,
                         float* __restrict__ gi) {
    __shared__ __align__(16) uint4 hfr[512];
    __shared__ __align__(16) float tot[16 * 772];
    int tid = threadIdx.x;
    int lane = tid & 63, w = tid >> 6, quad = lane >> 4, l16 = lane & 15;
    int s0 = blockIdx.x * NSB;

    uint4 frag[32];
    {
        const _Float16* base = Uh + (w * 64 + l16) * HD;
#pragma unroll
        for (int t = 0; t < 4; ++t)
#pragma unroll
            for (int kt = 0; kt < 8; ++kt)
                frag[t * 8 + kt] = *(const uint4*)(base + t * 16 * HD + kt * 32 + quad * 8);
    }

    int us = tid >> 5;
    int jg = tid & 31;
    int j0 = jg * 8;
    int hcell = (j0 >> 5) * 64 + 16 * ((j0 >> 3) & 3) + us;
    uint4 hcp;
    bool act = (tid < 512);
    bool real = act && (us < NSB);

    if (act) {
        if (real) {
            const unsigned short* prow = pre + ((long)(s0 + us) * LW + 63) * TH;
            float iv[8], uv[8], hcv[8];
            load8bf(prow + 256 + j0, iv);
            load8bf(prow + 512 + j0, uv);
#pragma unroll
            for (int r = 0; r < 8; ++r) hcv[r] = tanh_(sigm(iv[r]) * tanh_(uv[r]));
            hcp.x = pack_h2(hcv[0], hcv[1]); hcp.y = pack_h2(hcv[2], hcv[3]);
            hcp.z = pack_h2(hcv[4], hcv[5]); hcp.w = pack_h2(hcv[6], hcv[7]);
        } else {
            hcp.x = 0u; hcp.y = 0u; hcp.z = 0u; hcp.w = 0u;  // zero-pad cols NSB..15
        }
        hfr[hcell] = hcp;
    }
    __syncthreads();

    int mb = w * 64 + quad * 4;

    for (int step = 0; step < 63; ++step) {
        int l = 62 - step;
        uint2 praw[6];
        if (real) {
            const unsigned short* prow = pre + ((long)(s0 + us) * LW + l) * TH;
#pragma unroll
            for (int g = 0; g < 3; ++g) {
                praw[2 * g]     = *(const uint2*)(prow + g * 256 + j0);
                praw[2 * g + 1] = *(const uint2*)(prow + g * 256 + j0 + 4);
            }
        }
        f4 a0 = (f4){0,0,0,0}, a1 = (f4){0,0,0,0}, a2 = (f4){0,0,0,0}, a3 = (f4){0,0,0,0};
#pragma unroll
        for (int kt = 0; kt < 8; ++kt) {
            half8 b = __builtin_bit_cast(half8, hfr[kt * 64 + lane]);
            a0 = __builtin_amdgcn_mfma_f32_16x16x32_f16(__builtin_bit_cast(half8, frag[kt]), b, a0, 0, 0, 0);
            a1 = __builtin_amdgcn_mfma_f32_16x16x32_f16(__builtin_bit_cast(half8, frag[8 + kt]), b, a1, 0, 0, 0);
            a2 = __builtin_amdgcn_mfma_f32_16x16x32_f16(__builtin_bit_cast(half8, frag[16 + kt]), b, a2, 0, 0, 0);
            a3 = __builtin_amdgcn_mfma_f32_16x16x32_f16(__builtin_bit_cast(half8, frag[24 + kt]), b, a3, 0, 0, 0);
        }
        float* tr = tot + l16 * 772;
        *(f4*)&tr[mb] = a0;
        *(f4*)&tr[mb + 16] = a1;
        *(f4*)&tr[mb + 32] = a2;
        *(f4*)&tr[mb + 48] = a3;
        BAR_LDS();
        if (real) {
            const float* ts = tot + us * 772;
            float hcv[8];
            h2 px = __builtin_bit_cast(h2, hcp.x); h2 py = __builtin_bit_cast(h2, hcp.y);
            h2 pz = __builtin_bit_cast(h2, hcp.z); h2 pw = __builtin_bit_cast(h2, hcp.w);
            hcv[0] = (float)px.x; hcv[1] = (float)px.y; hcv[2] = (float)py.x; hcv[3] = (float)py.y;
            hcv[4] = (float)pz.x; hcv[5] = (float)pz.y; hcv[6] = (float)pw.x; hcv[7] = (float)pw.y;
#pragma unroll
            for (int hf = 0; hf < 2; ++hf) {
                int jb = j0 + hf * 4;
                float pf[4], pi_[4], pu[4];
                ubf4(praw[hf], pf);
                ubf4(praw[2 + hf], pi_);
                ubf4(praw[4 + hf], pu);
                f4 tf = *(const f4*)&ts[jb];
                f4 ti = *(const f4*)&ts[256 + jb];
                f4 tu = *(const f4*)&ts[512 + jb];
#pragma unroll
                for (int r = 0; r < 4; ++r) {
                    float ff = tf[r] + pf[r];
                    float ii = ti[r] + pi_[r];
                    float uu = tu[r] + pu[r];
                    hcv[hf * 4 + r] = tanh_(sigm(ii) * tanh_(uu) + sigm(ff) * hcv[hf * 4 + r]);
                }
            }
            hcp.x = pack_h2(hcv[0], hcv[1]); hcp.y = pack_h2(hcv[2], hcv[3]);
            hcp.z = pack_h2(hcv[4], hcv[5]); hcp.w = pack_h2(hcv[6], hcv[7]);
            hfr[hcell] = hcp;
        }
        BAR_LDS();
    }

    {
        const _Float16* base = Wihh + (w * 64 + l16) * HD;
#pragma unroll
        for (int t = 0; t < 4; ++t)
#pragma unroll
            for (int kt = 0; kt < 8; ++kt)
                frag[t * 8 + kt] = *(const uint4*)(base + t * 16 * HD + kt * 32 + quad * 8);
    }
    f4 a0 = (f4){0,0,0,0}, a1 = (f4){0,0,0,0}, a2 = (f4){0,0,0,0}, a3 = (f4){0,0,0,0};
#pragma unroll
    for (int kt = 0; kt < 8; ++kt) {
        half8 b = __builtin_bit_cast(half8, hfr[kt * 64 + lane]);
        a0 = __builtin_amdgcn_mfma_f32_16x16x32_f16(__builtin_bit_cast(half8, frag[kt]), b, a0, 0, 0, 0);
        a1 = __builtin_amdgcn_mfma_f32_16x16x32_f16(__builtin_bit_cast(half8, frag[8 + kt]), b, a1, 0, 0, 0);
        a2 = __builtin_amdgcn_mfma_f32_16x16x32_f16(__builtin_bit_cast(half8, frag[16 + kt]), b, a2, 0, 0, 0);
        a3 = __builtin_amdgcn_mfma_f32_16x16x32_f16(__builtin_bit_cast(half8, frag[24 + kt]), b, a3, 0, 0, 0);
    }
    if (l16 < NSB) {
        float* go = gi + (long)(s0 + l16) * TH;
        f4 b0 = *(const f4*)(bias2 + mb);
        f4 b1 = *(const f4*)(bias2 + mb + 16);
        f4 b2 = *(const f4*)(bias2 + mb + 32);
        f4 b3 = *(const f4*)(bias2 + mb + 48);
        *(f4*)(go + mb) = a0 + b0;
        *(f4*)(go + mb + 16) = a1 + b1;
        *(f4*)(go + mb + 32) = a2 + b2;
        *(f4*)(go + mb + 48) = a3 + b3;
    }
}

// ---------------- GRU v19: v17 inner loop (builtin MFMA) split into 4 x 256 steps ----------------
#define GB 8
__global__ void __launch_bounds__(512) k_gru(
                      const signed char* __restrict__ Wq, const float* __restrict__ rowscale,
                      const float* __restrict__ bhh,
                      const float* __restrict__ gi, const float* __restrict__ h0,
                      const float* __restrict__ tv,
                      const float* __restrict__ gateW, const float* __restrict__ gateU,
                      const float* __restrict__ gateb,
                      const float* __restrict__ outW, const float* __restrict__ outb,
                      float* __restrict__ out,
                      float* __restrict__ hstate, int t0, int do_head) {
    __shared__ __align__(16) signed char qbuf[2][HD]; // ping-pong h (i8, scale SH/127)
    __shared__ __align__(16) float gbuf[2][GB * TH];  // 48KB gi staging, double-buffered
    __shared__ float hts[HD];
    __shared__ float sgs[512];
    __shared__ float vvs[HD];
    __shared__ float lg[8];

    int tid = threadIdx.x;
    int lane = tid & 63, w = tid >> 6, quad = lane >> 4, l16 = lane & 15;

    // i8 fragments: r tiles rows w*32+c*16, z tiles 256+..., n tiles 512+... (v9 layout)
    i4 far_[2][4], faz[2][4], fan[2][4];
#pragma unroll
    for (int c = 0; c < 2; ++c) {
        const signed char* qr_ = Wq + (long)(w * 32 + c * 16 + l16) * HD;
        const signed char* qz_ = Wq + (long)(256 + w * 32 + c * 16 + l16) * HD;
        const signed char* qn_ = Wq + (long)(512 + w * 32 + c * 16 + l16) * HD;
#pragma unroll
        for (int kc = 0; kc < 4; ++kc) {
            far_[c][kc] = *(const i4*)(qr_ + kc * 64 + quad * 16);
            faz[c][kc] = *(const i4*)(qz_ + kc * 64 + quad * 16);
            fan[c][kc] = *(const i4*)(qn_ + kc * 64 + quad * 16);
        }
    }

    // per-lane ownership: h index j = w*32 + sc*16 + quad*4 + sr  (l16<8 unique)
    int sc = (l16 >> 2) & 1;
    int sr = l16 & 3;
    int j = w * 32 + sc * 16 + quad * 4 + sr;
    bool b2 = (sr & 2) != 0, b1 = (sr & 1) != 0, bc = (sc != 0);
    bool owner = (l16 < 8);

    float rs_r = rowscale[j];
    float rs_z = rowscale[256 + j];
    float rs_n = rowscale[512 + j];
    float bn_l = bhh[512 + j];

    float hv = (t0 == 0) ? h0[j] : hstate[j];
    if (owner) {
        float hc = fminf(fmaxf(hv, -SH), SH);
        qbuf[0][j] = (signed char)(int)rintf(hc * (127.f / SH));
    }
    // stage gi block nb0 directly; issue block nb0+1 into registers
    const int nb0 = t0 / GB;
    float rg[12];
    {
        const float* g0 = gi + (long)nb0 * GB * TH;
        const float* g1 = gi + (long)(nb0 + 1) * GB * TH;
#pragma unroll
        for (int i = 0; i < 12; ++i) gbuf[0][i * 512 + tid] = g0[i * 512 + tid];
#pragma unroll
        for (int i = 0; i < 12; ++i) rg[i] = g1[i * 512 + tid];
    }
    __syncthreads();

    for (int nbr = 0; nbr < 256 / GB; ++nbr) {
        int nb = nb0 + nbr;
        int buf = nbr & 1;
#pragma unroll
        for (int u = 0; u < GB; ++u) {
            if (u == 0) {
                // commit block nb+1 (in rg) to the other buffer; issue block nb+2
#pragma unroll
                for (int i = 0; i < 12; ++i) gbuf[buf ^ 1][i * 512 + tid] = rg[i];
                if (nb + 2 < NS / GB) {
                    const float* gsrc = gi + (long)(nb + 2) * GB * TH;
#pragma unroll
                    for (int i = 0; i < 12; ++i) rg[i] = gsrc[i * 512 + tid];
                }
            }
            const int p = u & 1;   // parity compile-time (t0 and GB both even multiples)
            const float* gl = &gbuf[buf][u * TH];
            float gr_l = gl[j], gz_l = gl[256 + j], gn_l = gl[512 + j];

            i4 qr[2], qz[2], qn[2];
#pragma unroll
            for (int c = 0; c < 2; ++c) { qr[c] = (i4){0,0,0,0}; qz[c] = (i4){0,0,0,0}; qn[c] = (i4){0,0,0,0}; }
#pragma unroll
            for (int kc = 0; kc < 4; ++kc) {
                i4 b = *(const i4*)&qbuf[p][kc * 64 + quad * 16];
                qr[0] = __builtin_amdgcn_mfma_i32_16x16x64_i8(far_[0][kc], b, qr[0], 0, 0, 0);
                qr[1] = __builtin_amdgcn_mfma_i32_16x16x64_i8(far_[1][kc], b, qr[1], 0, 0, 0);
                qz[0] = __builtin_amdgcn_mfma_i32_16x16x64_i8(faz[0][kc], b, qz[0], 0, 0, 0);
                qz[1] = __builtin_amdgcn_mfma_i32_16x16x64_i8(faz[1][kc], b, qz[1], 0, 0, 0);
                qn[0] = __builtin_amdgcn_mfma_i32_16x16x64_i8(fan[0][kc], b, qn[0], 0, 0, 0);
                qn[1] = __builtin_amdgcn_mfma_i32_16x16x64_i8(fan[1][kc], b, qn[1], 0, 0, 0);
            }
            // lane-select the (sc, sr) value from the 8 replicated D values
            int ra0 = bc ? qr[1][0] : qr[0][0], ra1 = bc ? qr[1][1] : qr[0][1];
            int ra2 = bc ? qr[1][2] : qr[0][2], ra3 = bc ? qr[1][3] : qr[0][3];
            int rt0 = b2 ? ra2 : ra0, rt1 = b2 ? ra3 : ra1;
            int qrv = b1 ? rt1 : rt0;
            int za0 = bc ? qz[1][0] : qz[0][0], za1 = bc ? qz[1][1] : qz[0][1];
            int za2 = bc ? qz[1][2] : qz[0][2], za3 = bc ? qz[1][3] : qz[0][3];
            int zt0 = b2 ? za2 : za0, zt1 = b2 ? za3 : za1;
            int qzv = b1 ? zt1 : zt0;
            int na0 = bc ? qn[1][0] : qn[0][0], na1 = bc ? qn[1][1] : qn[0][1];
            int na2 = bc ? qn[1][2] : qn[0][2], na3 = bc ? qn[1][3] : qn[0][3];
            int nt0 = b2 ? na2 : na0, nt1 = b2 ? na3 : na1;
            int qnv = b1 ? nt1 : nt0;
            // single gate update per lane
            float rv = sigm(gr_l + (float)qrv * rs_r);
            float zv = sigm(gz_l + (float)qzv * rs_z);
            float nv = tanh_(gn_l + rv * ((float)qnv * rs_n + bn_l));
            hv = (1.f - zv) * nv + zv * hv;
            if (owner) {
                float hc = fminf(fmaxf(hv, -SH), SH);
                qbuf[p ^ 1][j] = (signed char)(int)rintf(hc * (127.f / SH));
            }
            __syncthreads();
        }
    }

    if (!do_head) {
        // hand off h to the next dispatch (owners cover all 256 j)
        if (owner) hstate[j] = hv;
        return;
    }

    // head
    if (owner) hts[j] = hv;
    __syncthreads();
    {
        float s = gateb[tid];
        for (int k = 0; k < HD; ++k)
            s += gateW[tid * HD + k] * hts[k] + gateU[tid * HD + k] * tv[k];
        sgs[tid] = sigm(s);
    }
    __syncthreads();
    if (tid < HD) vvs[tid] = tanh_(sgs[tid] * hts[tid] + sgs[256 + tid] * tv[tid]);
    __syncthreads();
    if (tid < 5) {
        float s = outb[tid];
        for (int k = 0; k < HD; ++k) s += outW[tid * HD + k] * vvs[k];
        lg[tid] = s;
    }
    __syncthreads();
    if (tid == 0) {
        float m = lg[0];
        for (int i = 1; i < 5; ++i) m = fmaxf(m, lg[i]);
        float e[5], sum = 0.f;
        for (int i = 0; i < 5; ++i) { e[i] = __expf(lg[i] - m); sum += e[i]; }
        for (int i = 0; i < 5; ++i) out[i] = e[i] / sum;
    }
}

extern "C" void kernel_launch(void* const* d_in, const int* in_sizes, int n_in,
                              void* d_out, int out_size, void* d_ws, size_t ws_size,
                              hipStream_t stream) {
    (void)in_sizes; (void)n_in; (void)out_size; (void)ws_size;
    const int* sIdx = (const int*)d_in[0];
    const int* depT = (const int*)d_in[1];
    const float* DT = (const float*)d_in[2];
    const float* h0 = (const float*)d_in[3];
    const float* emb = (const float*)d_in[4];
    const float* q = (const float*)d_in[5];
    const float* W = (const float*)d_in[6];
    const float* U = (const float*)d_in[7];
    const float* Dm = (const float*)d_in[8];
    const float* b = (const float*)d_in[9];
    const float* Wih = (const float*)d_in[10];
    const float* Whh = (const float*)d_in[11];
    const float* bih = (const float*)d_in[12];
    const float* bhh = (const float*)d_in[13];
    const float* gateW = (const float*)d_in[14];
    const float* gateU = (const float*)d_in[15];
    const float* gateb = (const float*)d_in[16];
    const float* mlpW = (const float*)d_in[17];
    const float* mlpb = (const float*)d_in[18];
    const float* outW = (const float*)d_in[19];
    const float* outb = (const float*)d_in[20];

    char* ws = (char*)d_ws;
    unsigned short* Wb = (unsigned short*)ws;   ws += 768 * 320 * 2;
    _Float16* Uh = (_Float16*)ws;               ws += 768 * 256 * 2;
    _Float16* Wihh = (_Float16*)ws;             ws += 768 * 256 * 2;
    signed char* Wq = (signed char*)ws;         ws += 768 * 256;
    float* rowscale = (float*)ws;               ws += 768 * 4;
    float* bias2 = (float*)ws;                  ws += 768 * 4;
    float* Dq = (float*)ws;                     ws += 10 * 768 * 4;
    float* tv = (float*)ws;                     ws += 1024;
    float* hstate = (float*)ws;                 ws += 1024;
    ws = (char*)d_ws + ((((size_t)(ws - (char*)d_ws)) + 4095) & ~(size_t)4095);
    unsigned short* pre = (unsigned short*)ws;  ws += (size_t)65536 * 768 * 2;
    float* gi = (float*)ws;                     ws += (size_t)1024 * 768 * 4;

    k_prep<<<dim3(799), dim3(256), 0, stream>>>(W, U, Wih, Whh, q, Dm, DT, mlpW, mlpb,
                                                bih, bhh,
                                                Wb, Uh, Wihh, Wq, rowscale, bias2, Dq, tv);
    k_phaseB<<<dim3(2048), dim3(256), 0, stream>>>(sIdx, depT, emb, Wb, Dq, b, pre);
    k_phaseC<<<dim3(256), dim3(768), 0, stream>>>(pre, Uh, Wihh, bias2, gi);
    k_gru<<<dim3(1), dim3(512), 0, stream>>>(Wq, rowscale, bhh, gi, h0, tv,
                                             gateW, gateU, gateb, outW, outb, (float*)d_out,
                                             hstate, 0, 0);
    k_gru<<<dim3(1), dim3(512), 0, stream>>>(Wq, rowscale, bhh, gi, h0, tv,
                                             gateW, gateU, gateb, outW, outb, (float*)d_out,
                                             hstate, 256, 0);
    k_gru<<<dim3(1), dim3(512), 0, stream>>>(Wq, rowscale, bhh, gi, h0, tv,
                                             gateW, gateU, gateb, outW, outb, (float*)d_out,
                                             hstate, 512, 0);
    k_gru<<<dim3(1), dim3(512), 0, stream>>>(Wq, rowscale, bhh, gi, h0, tv,
                                             gateW, gateU, gateb, outW, outb, (float*)d_out,
                                             hstate, 768, 1);
}

// Round 14
// 1130.218 us; speedup vs baseline: 1.0900x; 1.0900x over previous
//
#include <hip/hip_runtime.h>

typedef short short8 __attribute__((ext_vector_type(8)));
typedef float f4 __attribute__((ext_vector_type(4)));
typedef int i4 __attribute__((ext_vector_type(4)));
typedef _Float16 half8 __attribute__((ext_vector_type(8)));
typedef _Float16 h2 __attribute__((ext_vector_type(2)));

#define HD 256
#define ED 300
#define EP 320
#define TH 768
#define NS 1024
#define LW 64
#define SH 4.5f

#define BAR_LDS() do { asm volatile("s_waitcnt lgkmcnt(0)" ::: "memory"); \
                       __builtin_amdgcn_s_barrier(); } while (0)

__device__ __forceinline__ unsigned short f2bf(float f) {
    unsigned int u = __float_as_uint(f);
    u = (u + 0x7FFFu + ((u >> 16) & 1u)) >> 16;
    return (unsigned short)u;
}
__device__ __forceinline__ float bf2f(unsigned short s) {
    return __uint_as_float(((unsigned int)s) << 16);
}
__device__ __forceinline__ float sigm(float x) {
    return __builtin_amdgcn_rcpf(1.f + __expf(-x));
}
__device__ __forceinline__ float tanh_(float x) {
    x = fminf(fmaxf(x, -15.f), 15.f);
    return 1.f - 2.f * __builtin_amdgcn_rcpf(1.f + __expf(2.f * x));
}
__device__ __forceinline__ unsigned int pack_h2(float a, float b) {
    h2 p; p.x = (_Float16)a; p.y = (_Float16)b;
    return __builtin_bit_cast(unsigned int, p);
}

__device__ __forceinline__ void load8bf(const unsigned short* p, float* o) {
    uint4 a = *(const uint4*)p;
    o[0] = bf2f((unsigned short)(a.x & 0xffff)); o[1] = bf2f((unsigned short)(a.x >> 16));
    o[2] = bf2f((unsigned short)(a.y & 0xffff)); o[3] = bf2f((unsigned short)(a.y >> 16));
    o[4] = bf2f((unsigned short)(a.z & 0xffff)); o[5] = bf2f((unsigned short)(a.z >> 16));
    o[6] = bf2f((unsigned short)(a.w & 0xffff)); o[7] = bf2f((unsigned short)(a.w >> 16));
}
__device__ __forceinline__ void ubf4(uint2 a, float* o) {
    o[0] = bf2f((unsigned short)(a.x & 0xffff)); o[1] = bf2f((unsigned short)(a.x >> 16));
    o[2] = bf2f((unsigned short)(a.y & 0xffff)); o[3] = bf2f((unsigned short)(a.y >> 16));
}

// ---------------- prep: weight conversions, i8 quantization (ALL 768 Whh rows), Dq, topic ----------------
__global__ void k_prep(const float* __restrict__ W, const float* __restrict__ U,
                       const float* __restrict__ Wih, const float* __restrict__ Whh,
                       const float* __restrict__ q, const float* __restrict__ Dm,
                       const float* __restrict__ DT, const float* __restrict__ mlpW,
                       const float* __restrict__ mlpb,
                       const float* __restrict__ bih, const float* __restrict__ bhh,
                       unsigned short* __restrict__ Wb, _Float16* __restrict__ Uh,
                       _Float16* __restrict__ Wihh,
                       signed char* __restrict__ Wq, float* __restrict__ rowscale,
                       float* __restrict__ bias2,
                       float* __restrict__ Dq, float* __restrict__ tv) {
    __shared__ float smax[4];
    int bid = blockIdx.x, tid = threadIdx.x;
    if (bid < 768) {
        int r = bid;
        for (int j = tid; j < EP; j += 256)
            Wb[r * EP + j] = (j < ED) ? f2bf(W[r * ED + j]) : (unsigned short)0;
        float whv = Whh[r * HD + tid];
        for (int j = tid; j < HD; j += 256) {
            Uh[r * HD + j] = (_Float16)U[r * HD + j];
            Wihh[r * HD + j] = (_Float16)Wih[r * HD + j];
        }
        // per-row i8 quantization of ALL Whh rows
        float v = fabsf(whv);
        for (int o = 32; o; o >>= 1) v = fmaxf(v, __shfl_xor(v, o));
        if ((tid & 63) == 0) smax[tid >> 6] = v;
        __syncthreads();
        float am = fmaxf(fmaxf(smax[0], smax[1]), fmaxf(smax[2], smax[3]));
        float inv = (am > 0.f) ? 127.f / am : 0.f;
        int qi = (int)rintf(whv * inv);
        qi = max(-127, min(127, qi));
        Wq[r * HD + tid] = (signed char)qi;
        if (tid == 0) rowscale[r] = (am / 127.f) * (SH / 127.f);
    } else if (bid < 798) {
        int idx = bid - 768;
        int d = idx / 3, part = idx - d * 3;
        int n = part * 256 + tid;
        float s = 0.f;
        for (int h = 0; h < HD; ++h) s += Dm[n * HD + h] * q[d * HD + h];
        Dq[d * TH + n] = s;
    } else {
        if (tid < HD) {
            float s = 0.f;
            for (int k = 0; k < 100; ++k) s += mlpW[tid * 100 + k] * DT[k];
            tv[tid] = tanh_(s + mlpb[tid]);
        }
        for (int r = tid; r < TH; r += 256)
            bias2[r] = bih[r] + ((r < 512) ? bhh[r] : 0.f);
    }
}

// ---------------- phase B v6: v5 structure, launch_bounds(256,3) to stop the acc spill ----------------
// r13 counters: VGPR_Count=64 < 96 needed by acc[2][12] -> launch_bounds(256,4)'s ~128-reg cap
// spilled the MFMA accumulators to scratch. The 630-730MB "write amplification" in v4 AND v5
// was SCRATCH TRAFFIC, not partial-line stores (r12 diagnosis wrong). v3 was clean only because
// (256,2) gave a 256-reg cap. v6: (256,3) -> ~170-reg cap >= ~140 needed -> no spill, 3
// blocks/CU (25KB LDS x 3 = 75KB). Verify: VGPR ~130-170, WRITE ~98MB.
#define XP 328
__launch_bounds__(256, 3)
__global__ void k_phaseB(const int* __restrict__ sIdx, const int* __restrict__ depT,
                         const float* __restrict__ emb, const unsigned short* __restrict__ Wb,
                         const float* __restrict__ Dq, const float* __restrict__ bias,
                         unsigned short* __restrict__ pre) {
    __shared__ __align__(16) unsigned short sbuf[16 * 776]; // 24832B; xbf needs 20992B
    unsigned short* xbf = sbuf;
    unsigned short* tbuf = sbuf;
    int tid = threadIdx.x;
    int c0 = blockIdx.x * 32;

    // stage 32 gathered x rows as bf16 (float4 loads; emb rows are 1200B = 75x16B aligned)
    for (int i = tid; i < 32 * 80; i += 256) {
        int row = i / 80, c4 = i - row * 80;
        unsigned int lo = 0, hi = 0;
        if (c4 < 75) {
            int idx = sIdx[c0 + row];
            float4 v = *(const float4*)(emb + (long)idx * ED + c4 * 4);
            lo = (unsigned int)f2bf(v.x) | ((unsigned int)f2bf(v.y) << 16);
            hi = (unsigned int)f2bf(v.z) | ((unsigned int)f2bf(v.w) << 16);
        }
        uint2 pv; pv.x = lo; pv.y = hi;
        *(uint2*)&xbf[row * XP + c4 * 4] = pv;
    }
    __syncthreads();

    int lane = tid & 63;
    int w = tid >> 6;
    int quad = lane >> 4, l16 = lane & 15;

    f4 acc[2][12];
#pragma unroll
    for (int cs = 0; cs < 2; ++cs)
#pragma unroll
        for (int ms = 0; ms < 12; ++ms) acc[cs][ms] = (f4){0.f, 0.f, 0.f, 0.f};

    const unsigned short* wbase = Wb + (w * 192 + l16) * EP;

#pragma unroll
    for (int kt = 0; kt < 10; ++kt) {
        int k0 = kt * 32 + quad * 8;
        short8 bf0 = *(const short8*)&xbf[l16 * XP + k0];
        short8 bf1 = *(const short8*)&xbf[(16 + l16) * XP + k0];
#pragma unroll
        for (int ms = 0; ms < 12; ++ms) {
            short8 af = *(const short8*)(wbase + ms * 16 * EP + k0);
            acc[0][ms] = __builtin_amdgcn_mfma_f32_16x16x32_bf16(af, bf0, acc[0][ms], 0, 0, 0);
            acc[1][ms] = __builtin_amdgcn_mfma_f32_16x16x32_bf16(af, bf1, acc[1][ms], 0, 0, 0);
        }
    }
    __syncthreads();   // xbf dead from here; sbuf becomes tbuf

#pragma unroll
    for (int cs = 0; cs < 2; ++cs) {
        int xr = c0 + cs * 16 + l16;
        int l = xr & 63, s = xr >> 6;
        int dep = (l == 63) ? 9 : depT[s * 63 + l];
        const float* dqrow = Dq + dep * TH;
#pragma unroll
        for (int ms = 0; ms < 12; ++ms) {
            int ncol = w * 192 + ms * 16 + quad * 4;
            f4 dq4 = *(const f4*)&dqrow[ncol];    // L2-resident (30KB table)
            f4 b4 = *(const f4*)&bias[ncol];
            unsigned int lo = (unsigned int)f2bf(acc[cs][ms][0] + dq4[0] + b4[0]) |
                              ((unsigned int)f2bf(acc[cs][ms][1] + dq4[1] + b4[1]) << 16);
            unsigned int hi = (unsigned int)f2bf(acc[cs][ms][2] + dq4[2] + b4[2]) |
                              ((unsigned int)f2bf(acc[cs][ms][3] + dq4[3] + b4[3]) << 16);
            uint2 v; v.x = lo; v.y = hi;
            *(uint2*)&tbuf[l16 * 776 + ncol] = v;
        }
        __syncthreads();
        // coalesced row-major store: 16 rows x 96 uint4 chunks = 1536 / 256 thr = 6 iters
        for (int it = 0; it < 6; ++it) {
            int flat = it * 256 + tid;
            int row = flat / 96;
            int ch = flat - row * 96;
            uint4 v = *(const uint4*)&tbuf[row * 776 + ch * 8];
            *(uint4*)(pre + (long)(c0 + cs * 16 + row) * TH + ch * 8) = v;
        }
        __syncthreads();
    }
}

// ---------------- phase C v2: 4 sentences/block x 256 blocks (full-chip), raw LDS barriers ----------------
#define NSB 4
__global__ void __launch_bounds__(768) k_phaseC(
                         const unsigned short* __restrict__ pre,
                         const _Float16* __restrict__ Uh,
                         const _Float16* __restrict__ Wihh,
                         const float* __restrict__ bias2,
                         float* __restrict__ gi) {
    __shared__ __align__(16) uint4 hfr[512];
    __shared__ __align__(16) float tot[16 * 772];
    int tid = threadIdx.x;
    int lane = tid & 63, w = tid >> 6, quad = lane >> 4, l16 = lane & 15;
    int s0 = blockIdx.x * NSB;

    uint4 frag[32];
    {
        const _Float16* base = Uh + (w * 64 + l16) * HD;
#pragma unroll
        for (int t = 0; t < 4; ++t)
#pragma unroll
            for (int kt = 0; kt < 8; ++kt)
                frag[t * 8 + kt] = *(const uint4*)(base + t * 16 * HD + kt * 32 + quad * 8);
    }

    int us = tid >> 5;
    int jg = tid & 31;
    int j0 = jg * 8;
    int hcell = (j0 >> 5) * 64 + 16 * ((j0 >> 3) & 3) + us;
    uint4 hcp;
    bool act = (tid < 512);
    bool real = act && (us < NSB);

    if (act) {
        if (real) {
            const unsigned short* prow = pre + ((long)(s0 + us) * LW + 63) * TH;
            float iv[8], uv[8], hcv[8];
            load8bf(prow + 256 + j0, iv);
            load8bf(prow + 512 + j0, uv);
#pragma unroll
            for (int r = 0; r < 8; ++r) hcv[r] = tanh_(sigm(iv[r]) * tanh_(uv[r]));
            hcp.x = pack_h2(hcv[0], hcv[1]); hcp.y = pack_h2(hcv[2], hcv[3]);
            hcp.z = pack_h2(hcv[4], hcv[5]); hcp.w = pack_h2(hcv[6], hcv[7]);
        } else {
            hcp.x = 0u; hcp.y = 0u; hcp.z = 0u; hcp.w = 0u;  // zero-pad cols NSB..15
        }
        hfr[hcell] = hcp;
    }
    __syncthreads();

    int mb = w * 64 + quad * 4;

    for (int step = 0; step < 63; ++step) {
        int l = 62 - step;
        uint2 praw[6];
        if (real) {
            const unsigned short* prow = pre + ((long)(s0 + us) * LW + l) * TH;
#pragma unroll
            for (int g = 0; g < 3; ++g) {
                praw[2 * g]     = *(const uint2*)(prow + g * 256 + j0);
                praw[2 * g + 1] = *(const uint2*)(prow + g * 256 + j0 + 4);
            }
        }
        f4 a0 = (f4){0,0,0,0}, a1 = (f4){0,0,0,0}, a2 = (f4){0,0,0,0}, a3 = (f4){0,0,0,0};
#pragma unroll
        for (int kt = 0; kt < 8; ++kt) {
            half8 b = __builtin_bit_cast(half8, hfr[kt * 64 + lane]);
            a0 = __builtin_amdgcn_mfma_f32_16x16x32_f16(__builtin_bit_cast(half8, frag[kt]), b, a0, 0, 0, 0);
            a1 = __builtin_amdgcn_mfma_f32_16x16x32_f16(__builtin_bit_cast(half8, frag[8 + kt]), b, a1, 0, 0, 0);
            a2 = __builtin_amdgcn_mfma_f32_16x16x32_f16(__builtin_bit_cast(half8, frag[16 + kt]), b, a2, 0, 0, 0);
            a3 = __builtin_amdgcn_mfma_f32_16x16x32_f16(__builtin_bit_cast(half8, frag[24 + kt]), b, a3, 0, 0, 0);
        }
        float* tr = tot + l16 * 772;
        *(f4*)&tr[mb] = a0;
        *(f4*)&tr[mb + 16] = a1;
        *(f4*)&tr[mb + 32] = a2;
        *(f4*)&tr[mb + 48] = a3;
        BAR_LDS();
        if (real) {
            const float* ts = tot + us * 772;
            float hcv[8];
            h2 px = __builtin_bit_cast(h2, hcp.x); h2 py = __builtin_bit_cast(h2, hcp.y);
            h2 pz = __builtin_bit_cast(h2, hcp.z); h2 pw = __builtin_bit_cast(h2, hcp.w);
            hcv[0] = (float)px.x; hcv[1] = (float)px.y; hcv[2] = (float)py.x; hcv[3] = (float)py.y;
            hcv[4] = (float)pz.x; hcv[5] = (float)pz.y; hcv[6] = (float)pw.x; hcv[7] = (float)pw.y;
#pragma unroll
            for (int hf = 0; hf < 2; ++hf) {
                int jb = j0 + hf * 4;
                float pf[4], pi_[4], pu[4];
                ubf4(praw[hf], pf);
                ubf4(praw[2 + hf], pi_);
                ubf4(praw[4 + hf], pu);
                f4 tf = *(const f4*)&ts[jb];
                f4 ti = *(const f4*)&ts[256 + jb];
                f4 tu = *(const f4*)&ts[512 + jb];
#pragma unroll
                for (int r = 0; r < 4; ++r) {
                    float ff = tf[r] + pf[r];
                    float ii = ti[r] + pi_[r];
                    float uu = tu[r] + pu[r];
                    hcv[hf * 4 + r] = tanh_(sigm(ii) * tanh_(uu) + sigm(ff) * hcv[hf * 4 + r]);
                }
            }
            hcp.x = pack_h2(hcv[0], hcv[1]); hcp.y = pack_h2(hcv[2], hcv[3]);
            hcp.z = pack_h2(hcv[4], hcv[5]); hcp.w = pack_h2(hcv[6], hcv[7]);
            hfr[hcell] = hcp;
        }
        BAR_LDS();
    }

    {
        const _Float16* base = Wihh + (w * 64 + l16) * HD;
#pragma unroll
        for (int t = 0; t < 4; ++t)
#pragma unroll
            for (int kt = 0; kt < 8; ++kt)
                frag[t * 8 + kt] = *(const uint4*)(base + t * 16 * HD + kt * 32 + quad * 8);
    }
    f4 a0 = (f4){0,0,0,0}, a1 = (f4){0,0,0,0}, a2 = (f4){0,0,0,0}, a3 = (f4){0,0,0,0};
#pragma unroll
    for (int kt = 0; kt < 8; ++kt) {
        half8 b = __builtin_bit_cast(half8, hfr[kt * 64 + lane]);
        a0 = __builtin_amdgcn_mfma_f32_16x16x32_f16(__builtin_bit_cast(half8, frag[kt]), b, a0, 0, 0, 0);
        a1 = __builtin_amdgcn_mfma_f32_16x16x32_f16(__builtin_bit_cast(half8, frag[8 + kt]), b, a1, 0, 0, 0);
        a2 = __builtin_amdgcn_mfma_f32_16x16x32_f16(__builtin_bit_cast(half8, frag[16 + kt]), b, a2, 0, 0, 0);
        a3 = __builtin_amdgcn_mfma_f32_16x16x32_f16(__builtin_bit_cast(half8, frag[24 + kt]), b, a3, 0, 0, 0);
    }
    if (l16 < NSB) {
        float* go = gi + (long)(s0 + l16) * TH;
        f4 b0 = *(const f4*)(bias2 + mb);
        f4 b1 = *(const f4*)(bias2 + mb + 16);
        f4 b2 = *(const f4*)(bias2 + mb + 32);
        f4 b3 = *(const f4*)(bias2 + mb + 48);
        *(f4*)(go + mb) = a0 + b0;
        *(f4*)(go + mb + 16) = a1 + b1;
        *(f4*)(go + mb + 32) = a2 + b2;
        *(f4*)(go + mb + 48) = a3 + b3;
    }
}

// ---------------- GRU v19: v17 inner loop (builtin MFMA) split into 4 x 256 steps ----------------
#define GB 8
__global__ void __launch_bounds__(512) k_gru(
                      const signed char* __restrict__ Wq, const float* __restrict__ rowscale,
                      const float* __restrict__ bhh,
                      const float* __restrict__ gi, const float* __restrict__ h0,
                      const float* __restrict__ tv,
                      const float* __restrict__ gateW, const float* __restrict__ gateU,
                      const float* __restrict__ gateb,
                      const float* __restrict__ outW, const float* __restrict__ outb,
                      float* __restrict__ out,
                      float* __restrict__ hstate, int t0, int do_head) {
    __shared__ __align__(16) signed char qbuf[2][HD]; // ping-pong h (i8, scale SH/127)
    __shared__ __align__(16) float gbuf[2][GB * TH];  // 48KB gi staging, double-buffered
    __shared__ float hts[HD];
    __shared__ float sgs[512];
    __shared__ float vvs[HD];
    __shared__ float lg[8];

    int tid = threadIdx.x;
    int lane = tid & 63, w = tid >> 6, quad = lane >> 4, l16 = lane & 15;

    // i8 fragments: r tiles rows w*32+c*16, z tiles 256+..., n tiles 512+... (v9 layout)
    i4 far_[2][4], faz[2][4], fan[2][4];
#pragma unroll
    for (int c = 0; c < 2; ++c) {
        const signed char* qr_ = Wq + (long)(w * 32 + c * 16 + l16) * HD;
        const signed char* qz_ = Wq + (long)(256 + w * 32 + c * 16 + l16) * HD;
        const signed char* qn_ = Wq + (long)(512 + w * 32 + c * 16 + l16) * HD;
#pragma unroll
        for (int kc = 0; kc < 4; ++kc) {
            far_[c][kc] = *(const i4*)(qr_ + kc * 64 + quad * 16);
            faz[c][kc] = *(const i4*)(qz_ + kc * 64 + quad * 16);
            fan[c][kc] = *(const i4*)(qn_ + kc * 64 + quad * 16);
        }
    }

    // per-lane ownership: h index j = w*32 + sc*16 + quad*4 + sr  (l16<8 unique)
    int sc = (l16 >> 2) & 1;
    int sr = l16 & 3;
    int j = w * 32 + sc * 16 + quad * 4 + sr;
    bool b2 = (sr & 2) != 0, b1 = (sr & 1) != 0, bc = (sc != 0);
    bool owner = (l16 < 8);

    float rs_r = rowscale[j];
    float rs_z = rowscale[256 + j];
    float rs_n = rowscale[512 + j];
    float bn_l = bhh[512 + j];

    float hv = (t0 == 0) ? h0[j] : hstate[j];
    if (owner) {
        float hc = fminf(fmaxf(hv, -SH), SH);
        qbuf[0][j] = (signed char)(int)rintf(hc * (127.f / SH));
    }
    // stage gi block nb0 directly; issue block nb0+1 into registers
    const int nb0 = t0 / GB;
    float rg[12];
    {
        const float* g0 = gi + (long)nb0 * GB * TH;
        const float* g1 = gi + (long)(nb0 + 1) * GB * TH;
#pragma unroll
        for (int i = 0; i < 12; ++i) gbuf[0][i * 512 + tid] = g0[i * 512 + tid];
#pragma unroll
        for (int i = 0; i < 12; ++i) rg[i] = g1[i * 512 + tid];
    }
    __syncthreads();

    for (int nbr = 0; nbr < 256 / GB; ++nbr) {
        int nb = nb0 + nbr;
        int buf = nbr & 1;
#pragma unroll
        for (int u = 0; u < GB; ++u) {
            if (u == 0) {
                // commit block nb+1 (in rg) to the other buffer; issue block nb+2
#pragma unroll
                for (int i = 0; i < 12; ++i) gbuf[buf ^ 1][i * 512 + tid] = rg[i];
                if (nb + 2 < NS / GB) {
                    const float* gsrc = gi + (long)(nb + 2) * GB * TH;
#pragma unroll
                    for (int i = 0; i < 12; ++i) rg[i] = gsrc[i * 512 + tid];
                }
            }
            const int p = u & 1;   // parity compile-time (t0 and GB both even multiples)
            const float* gl = &gbuf[buf][u * TH];
            float gr_l = gl[j], gz_l = gl[256 + j], gn_l = gl[512 + j];

            i4 qr[2], qz[2], qn[2];
#pragma unroll
            for (int c = 0; c < 2; ++c) { qr[c] = (i4){0,0,0,0}; qz[c] = (i4){0,0,0,0}; qn[c] = (i4){0,0,0,0}; }
#pragma unroll
            for (int kc = 0; kc < 4; ++kc) {
                i4 b = *(const i4*)&qbuf[p][kc * 64 + quad * 16];
                qr[0] = __builtin_amdgcn_mfma_i32_16x16x64_i8(far_[0][kc], b, qr[0], 0, 0, 0);
                qr[1] = __builtin_amdgcn_mfma_i32_16x16x64_i8(far_[1][kc], b, qr[1], 0, 0, 0);
                qz[0] = __builtin_amdgcn_mfma_i32_16x16x64_i8(faz[0][kc], b, qz[0], 0, 0, 0);
                qz[1] = __builtin_amdgcn_mfma_i32_16x16x64_i8(faz[1][kc], b, qz[1], 0, 0, 0);
                qn[0] = __builtin_amdgcn_mfma_i32_16x16x64_i8(fan[0][kc], b, qn[0], 0, 0, 0);
                qn[1] = __builtin_amdgcn_mfma_i32_16x16x64_i8(fan[1][kc], b, qn[1], 0, 0, 0);
            }
            // lane-select the (sc, sr) value from the 8 replicated D values
            int ra0 = bc ? qr[1][0] : qr[0][0], ra1 = bc ? qr[1][1] : qr[0][1];
            int ra2 = bc ? qr[1][2] : qr[0][2], ra3 = bc ? qr[1][3] : qr[0][3];
            int rt0 = b2 ? ra2 : ra0, rt1 = b2 ? ra3 : ra1;
            int qrv = b1 ? rt1 : rt0;
            int za0 = bc ? qz[1][0] : qz[0][0], za1 = bc ? qz[1][1] : qz[0][1];
            int za2 = bc ? qz[1][2] : qz[0][2], za3 = bc ? qz[1][3] : qz[0][3];
            int zt0 = b2 ? za2 : za0, zt1 = b2 ? za3 : za1;
            int qzv = b1 ? zt1 : zt0;
            int na0 = bc ? qn[1][0] : qn[0][0], na1 = bc ? qn[1][1] : qn[0][1];
            int na2 = bc ? qn[1][2] : qn[0][2], na3 = bc ? qn[1][3] : qn[0][3];
            int nt0 = b2 ? na2 : na0, nt1 = b2 ? na3 : na1;
            int qnv = b1 ? nt1 : nt0;
            // single gate update per lane
            float rv = sigm(gr_l + (float)qrv * rs_r);
            float zv = sigm(gz_l + (float)qzv * rs_z);
            float nv = tanh_(gn_l + rv * ((float)qnv * rs_n + bn_l));
            hv = (1.f - zv) * nv + zv * hv;
            if (owner) {
                float hc = fminf(fmaxf(hv, -SH), SH);
                qbuf[p ^ 1][j] = (signed char)(int)rintf(hc * (127.f / SH));
            }
            __syncthreads();
        }
    }

    if (!do_head) {
        // hand off h to the next dispatch (owners cover all 256 j)
        if (owner) hstate[j] = hv;
        return;
    }

    // head
    if (owner) hts[j] = hv;
    __syncthreads();
    {
        float s = gateb[tid];
        for (int k = 0; k < HD; ++k)
            s += gateW[tid * HD + k] * hts[k] + gateU[tid * HD + k] * tv[k];
        sgs[tid] = sigm(s);
    }
    __syncthreads();
    if (tid < HD) vvs[tid] = tanh_(sgs[tid] * hts[tid] + sgs[256 + tid] * tv[tid]);
    __syncthreads();
    if (tid < 5) {
        float s = outb[tid];
        for (int k = 0; k < HD; ++k) s += outW[tid * HD + k] * vvs[k];
        lg[tid] = s;
    }
    __syncthreads();
    if (tid == 0) {
        float m = lg[0];
        for (int i = 1; i < 5; ++i) m = fmaxf(m, lg[i]);
        float e[5], sum = 0.f;
        for (int i = 0; i < 5; ++i) { e[i] = __expf(lg[i] - m); sum += e[i]; }
        for (int i = 0; i < 5; ++i) out[i] = e[i] / sum;
    }
}

extern "C" void kernel_launch(void* const* d_in, const int* in_sizes, int n_in,
                              void* d_out, int out_size, void* d_ws, size_t ws_size,
                              hipStream_t stream) {
    (void)in_sizes; (void)n_in; (void)out_size; (void)ws_size;
    const int* sIdx = (const int*)d_in[0];
    const int* depT = (const int*)d_in[1];
    const float* DT = (const float*)d_in[2];
    const float* h0 = (const float*)d_in[3];
    const float* emb = (const float*)d_in[4];
    const float* q = (const float*)d_in[5];
    const float* W = (const float*)d_in[6];
    const float* U = (const float*)d_in[7];
    const float* Dm = (const float*)d_in[8];
    const float* b = (const float*)d_in[9];
    const float* Wih = (const float*)d_in[10];
    const float* Whh = (const float*)d_in[11];
    const float* bih = (const float*)d_in[12];
    const float* bhh = (const float*)d_in[13];
    const float* gateW = (const float*)d_in[14];
    const float* gateU = (const float*)d_in[15];
    const float* gateb = (const float*)d_in[16];
    const float* mlpW = (const float*)d_in[17];
    const float* mlpb = (const float*)d_in[18];
    const float* outW = (const float*)d_in[19];
    const float* outb = (const float*)d_in[20];

    char* ws = (char*)d_ws;
    unsigned short* Wb = (unsigned short*)ws;   ws += 768 * 320 * 2;
    _Float16* Uh = (_Float16*)ws;               ws += 768 * 256 * 2;
    _Float16* Wihh = (_Float16*)ws;             ws += 768 * 256 * 2;
    signed char* Wq = (signed char*)ws;         ws += 768 * 256;
    float* rowscale = (float*)ws;               ws += 768 * 4;
    float* bias2 = (float*)ws;                  ws += 768 * 4;
    float* Dq = (float*)ws;                     ws += 10 * 768 * 4;
    float* tv = (float*)ws;                     ws += 1024;
    float* hstate = (float*)ws;                 ws += 1024;
    ws = (char*)d_ws + ((((size_t)(ws - (char*)d_ws)) + 4095) & ~(size_t)4095);
    unsigned short* pre = (unsigned short*)ws;  ws += (size_t)65536 * 768 * 2;
    float* gi = (float*)ws;                     ws += (size_t)1024 * 768 * 4;

    k_prep<<<dim3(799), dim3(256), 0, stream>>>(W, U, Wih, Whh, q, Dm, DT, mlpW, mlpb,
                                                bih, bhh,
                                                Wb, Uh, Wihh, Wq, rowscale, bias2, Dq, tv);
    k_phaseB<<<dim3(2048), dim3(256), 0, stream>>>(sIdx, depT, emb, Wb, Dq, b, pre);
    k_phaseC<<<dim3(256), dim3(768), 0, stream>>>(pre, Uh, Wihh, bias2, gi);
    k_gru<<<dim3(1), dim3(512), 0, stream>>>(Wq, rowscale, bhh, gi, h0, tv,
                                             gateW, gateU, gateb, outW, outb, (float*)d_out,
                                             hstate, 0, 0);
    k_gru<<<dim3(1), dim3(512), 0, stream>>>(Wq, rowscale, bhh, gi, h0, tv,
                                             gateW, gateU, gateb, outW, outb, (float*)d_out,
                                             hstate, 256, 0);
    k_gru<<<dim3(1), dim3(512), 0, stream>>>(Wq, rowscale, bhh, gi, h0, tv,
                                             gateW, gateU, gateb, outW, outb, (float*)d_out,
                                             hstate, 512, 0);
    k_gru<<<dim3(1), dim3(512), 0, stream>>>(Wq, rowscale, bhh, gi, h0, tv,
                                             gateW, gateU, gateb, outW, outb, (float*)d_out,
                                             hstate, 768, 1);
}

// Round 15
// 1103.070 us; speedup vs baseline: 1.1168x; 1.0246x over previous
//
#include <hip/hip_runtime.h>

typedef short short8 __attribute__((ext_vector_type(8)));
typedef float f4 __attribute__((ext_vector_type(4)));
typedef int i4 __attribute__((ext_vector_type(4)));
typedef _Float16 half8 __attribute__((ext_vector_type(8)));
typedef _Float16 h2 __attribute__((ext_vector_type(2)));

#define HD 256
#define ED 300
#define EP 320
#define TH 768
#define NS 1024
#define LW 64
#define SH 4.5f

#define BAR_LDS() do { asm volatile("s_waitcnt lgkmcnt(0)" ::: "memory"); \
                       __builtin_amdgcn_s_barrier(); } while (0)

__device__ __forceinline__ unsigned short f2bf(float f) {
    unsigned int u = __float_as_uint(f);
    u = (u + 0x7FFFu + ((u >> 16) & 1u)) >> 16;
    return (unsigned short)u;
}
__device__ __forceinline__ float bf2f(unsigned short s) {
    return __uint_as_float(((unsigned int)s) << 16);
}
__device__ __forceinline__ float sigm(float x) {
    return __builtin_amdgcn_rcpf(1.f + __expf(-x));
}
__device__ __forceinline__ float tanh_(float x) {
    x = fminf(fmaxf(x, -15.f), 15.f);
    return 1.f - 2.f * __builtin_amdgcn_rcpf(1.f + __expf(2.f * x));
}
__device__ __forceinline__ unsigned int pack_h2(float a, float b) {
    h2 p; p.x = (_Float16)a; p.y = (_Float16)b;
    return __builtin_bit_cast(unsigned int, p);
}

__device__ __forceinline__ void load8bf(const unsigned short* p, float* o) {
    uint4 a = *(const uint4*)p;
    o[0] = bf2f((unsigned short)(a.x & 0xffff)); o[1] = bf2f((unsigned short)(a.x >> 16));
    o[2] = bf2f((unsigned short)(a.y & 0xffff)); o[3] = bf2f((unsigned short)(a.y >> 16));
    o[4] = bf2f((unsigned short)(a.z & 0xffff)); o[5] = bf2f((unsigned short)(a.z >> 16));
    o[6] = bf2f((unsigned short)(a.w & 0xffff)); o[7] = bf2f((unsigned short)(a.w >> 16));
}
__device__ __forceinline__ void ubf4(uint2 a, float* o) {
    o[0] = bf2f((unsigned short)(a.x & 0xffff)); o[1] = bf2f((unsigned short)(a.x >> 16));
    o[2] = bf2f((unsigned short)(a.y & 0xffff)); o[3] = bf2f((unsigned short)(a.y >> 16));
}

// ---------------- prep: weight conversions, i8 quantization (ALL 768 Whh rows), Dq, topic ----------------
__global__ void k_prep(const float* __restrict__ W, const float* __restrict__ U,
                       const float* __restrict__ Wih, const float* __restrict__ Whh,
                       const float* __restrict__ q, const float* __restrict__ Dm,
                       const float* __restrict__ DT, const float* __restrict__ mlpW,
                       const float* __restrict__ mlpb,
                       const float* __restrict__ bih, const float* __restrict__ bhh,
                       unsigned short* __restrict__ Wb, _Float16* __restrict__ Uh,
                       _Float16* __restrict__ Wihh,
                       signed char* __restrict__ Wq, float* __restrict__ rowscale,
                       float* __restrict__ bias2,
                       float* __restrict__ Dq, float* __restrict__ tv) {
    __shared__ float smax[4];
    int bid = blockIdx.x, tid = threadIdx.x;
    if (bid < 768) {
        int r = bid;
        for (int j = tid; j < EP; j += 256)
            Wb[r * EP + j] = (j < ED) ? f2bf(W[r * ED + j]) : (unsigned short)0;
        float whv = Whh[r * HD + tid];
        for (int j = tid; j < HD; j += 256) {
            Uh[r * HD + j] = (_Float16)U[r * HD + j];
            Wihh[r * HD + j] = (_Float16)Wih[r * HD + j];
        }
        // per-row i8 quantization of ALL Whh rows
        float v = fabsf(whv);
        for (int o = 32; o; o >>= 1) v = fmaxf(v, __shfl_xor(v, o));
        if ((tid & 63) == 0) smax[tid >> 6] = v;
        __syncthreads();
        float am = fmaxf(fmaxf(smax[0], smax[1]), fmaxf(smax[2], smax[3]));
        float inv = (am > 0.f) ? 127.f / am : 0.f;
        int qi = (int)rintf(whv * inv);
        qi = max(-127, min(127, qi));
        Wq[r * HD + tid] = (signed char)qi;
        if (tid == 0) rowscale[r] = (am / 127.f) * (SH / 127.f);
    } else if (bid < 798) {
        int idx = bid - 768;
        int d = idx / 3, part = idx - d * 3;
        int n = part * 256 + tid;
        float s = 0.f;
        for (int h = 0; h < HD; ++h) s += Dm[n * HD + h] * q[d * HD + h];
        Dq[d * TH + n] = s;
    } else {
        if (tid < HD) {
            float s = 0.f;
            for (int k = 0; k < 100; ++k) s += mlpW[tid * 100 + k] * DT[k];
            tv[tid] = tanh_(s + mlpb[tid]);
        }
        for (int r = tid; r < TH; r += 256)
            bias2[r] = bih[r] + ((r < 512) ? bhh[r] : 0.f);
    }
}

// ---------------- phase B v6: minimal LDS + coalesced writes + (256,3) no-spill ----------------
// r14 verified: WRITE 98MB, FETCH 47MB (spill gone; acc in AGPRs), 201us, Occ 29%.
#define XP 328
__launch_bounds__(256, 3)
__global__ void k_phaseB(const int* __restrict__ sIdx, const int* __restrict__ depT,
                         const float* __restrict__ emb, const unsigned short* __restrict__ Wb,
                         const float* __restrict__ Dq, const float* __restrict__ bias,
                         unsigned short* __restrict__ pre) {
    __shared__ __align__(16) unsigned short sbuf[16 * 776]; // 24832B; xbf needs 20992B
    unsigned short* xbf = sbuf;
    unsigned short* tbuf = sbuf;
    int tid = threadIdx.x;
    int c0 = blockIdx.x * 32;

    // stage 32 gathered x rows as bf16 (float4 loads; emb rows are 1200B = 75x16B aligned)
    for (int i = tid; i < 32 * 80; i += 256) {
        int row = i / 80, c4 = i - row * 80;
        unsigned int lo = 0, hi = 0;
        if (c4 < 75) {
            int idx = sIdx[c0 + row];
            float4 v = *(const float4*)(emb + (long)idx * ED + c4 * 4);
            lo = (unsigned int)f2bf(v.x) | ((unsigned int)f2bf(v.y) << 16);
            hi = (unsigned int)f2bf(v.z) | ((unsigned int)f2bf(v.w) << 16);
        }
        uint2 pv; pv.x = lo; pv.y = hi;
        *(uint2*)&xbf[row * XP + c4 * 4] = pv;
    }
    __syncthreads();

    int lane = tid & 63;
    int w = tid >> 6;
    int quad = lane >> 4, l16 = lane & 15;

    f4 acc[2][12];
#pragma unroll
    for (int cs = 0; cs < 2; ++cs)
#pragma unroll
        for (int ms = 0; ms < 12; ++ms) acc[cs][ms] = (f4){0.f, 0.f, 0.f, 0.f};

    const unsigned short* wbase = Wb + (w * 192 + l16) * EP;

#pragma unroll
    for (int kt = 0; kt < 10; ++kt) {
        int k0 = kt * 32 + quad * 8;
        short8 bf0 = *(const short8*)&xbf[l16 * XP + k0];
        short8 bf1 = *(const short8*)&xbf[(16 + l16) * XP + k0];
#pragma unroll
        for (int ms = 0; ms < 12; ++ms) {
            short8 af = *(const short8*)(wbase + ms * 16 * EP + k0);
            acc[0][ms] = __builtin_amdgcn_mfma_f32_16x16x32_bf16(af, bf0, acc[0][ms], 0, 0, 0);
            acc[1][ms] = __builtin_amdgcn_mfma_f32_16x16x32_bf16(af, bf1, acc[1][ms], 0, 0, 0);
        }
    }
    __syncthreads();   // xbf dead from here; sbuf becomes tbuf

#pragma unroll
    for (int cs = 0; cs < 2; ++cs) {
        int xr = c0 + cs * 16 + l16;
        int l = xr & 63, s = xr >> 6;
        int dep = (l == 63) ? 9 : depT[s * 63 + l];
        const float* dqrow = Dq + dep * TH;
#pragma unroll
        for (int ms = 0; ms < 12; ++ms) {
            int ncol = w * 192 + ms * 16 + quad * 4;
            f4 dq4 = *(const f4*)&dqrow[ncol];    // L2-resident (30KB table)
            f4 b4 = *(const f4*)&bias[ncol];
            unsigned int lo = (unsigned int)f2bf(acc[cs][ms][0] + dq4[0] + b4[0]) |
                              ((unsigned int)f2bf(acc[cs][ms][1] + dq4[1] + b4[1]) << 16);
            unsigned int hi = (unsigned int)f2bf(acc[cs][ms][2] + dq4[2] + b4[2]) |
                              ((unsigned int)f2bf(acc[cs][ms][3] + dq4[3] + b4[3]) << 16);
            uint2 v; v.x = lo; v.y = hi;
            *(uint2*)&tbuf[l16 * 776 + ncol] = v;
        }
        __syncthreads();
        // coalesced row-major store: 16 rows x 96 uint4 chunks = 1536 / 256 thr = 6 iters
        for (int it = 0; it < 6; ++it) {
            int flat = it * 256 + tid;
            int row = flat / 96;
            int ch = flat - row * 96;
            uint4 v = *(const uint4*)&tbuf[row * 776 + ch * 8];
            *(uint4*)(pre + (long)(c0 + cs * 16 + row) * TH + ch * 8) = v;
        }
        __syncthreads();
    }
}

// ---------------- phase C v2: 4 sentences/block x 256 blocks (full-chip), raw LDS barriers ----------------
#define NSB 4
__global__ void __launch_bounds__(768) k_phaseC(
                         const unsigned short* __restrict__ pre,
                         const _Float16* __restrict__ Uh,
                         const _Float16* __restrict__ Wihh,
                         const float* __restrict__ bias2,
                         float* __restrict__ gi) {
    __shared__ __align__(16) uint4 hfr[512];
    __shared__ __align__(16) float tot[16 * 772];
    int tid = threadIdx.x;
    int lane = tid & 63, w = tid >> 6, quad = lane >> 4, l16 = lane & 15;
    int s0 = blockIdx.x * NSB;

    uint4 frag[32];
    {
        const _Float16* base = Uh + (w * 64 + l16) * HD;
#pragma unroll
        for (int t = 0; t < 4; ++t)
#pragma unroll
            for (int kt = 0; kt < 8; ++kt)
                frag[t * 8 + kt] = *(const uint4*)(base + t * 16 * HD + kt * 32 + quad * 8);
    }

    int us = tid >> 5;
    int jg = tid & 31;
    int j0 = jg * 8;
    int hcell = (j0 >> 5) * 64 + 16 * ((j0 >> 3) & 3) + us;
    uint4 hcp;
    bool act = (tid < 512);
    bool real = act && (us < NSB);

    if (act) {
        if (real) {
            const unsigned short* prow = pre + ((long)(s0 + us) * LW + 63) * TH;
            float iv[8], uv[8], hcv[8];
            load8bf(prow + 256 + j0, iv);
            load8bf(prow + 512 + j0, uv);
#pragma unroll
            for (int r = 0; r < 8; ++r) hcv[r] = tanh_(sigm(iv[r]) * tanh_(uv[r]));
            hcp.x = pack_h2(hcv[0], hcv[1]); hcp.y = pack_h2(hcv[2], hcv[3]);
            hcp.z = pack_h2(hcv[4], hcv[5]); hcp.w = pack_h2(hcv[6], hcv[7]);
        } else {
            hcp.x = 0u; hcp.y = 0u; hcp.z = 0u; hcp.w = 0u;  // zero-pad cols NSB..15
        }
        hfr[hcell] = hcp;
    }
    __syncthreads();

    int mb = w * 64 + quad * 4;

    for (int step = 0; step < 63; ++step) {
        int l = 62 - step;
        uint2 praw[6];
        if (real) {
            const unsigned short* prow = pre + ((long)(s0 + us) * LW + l) * TH;
#pragma unroll
            for (int g = 0; g < 3; ++g) {
                praw[2 * g]     = *(const uint2*)(prow + g * 256 + j0);
                praw[2 * g + 1] = *(const uint2*)(prow + g * 256 + j0 + 4);
            }
        }
        f4 a0 = (f4){0,0,0,0}, a1 = (f4){0,0,0,0}, a2 = (f4){0,0,0,0}, a3 = (f4){0,0,0,0};
#pragma unroll
        for (int kt = 0; kt < 8; ++kt) {
            half8 b = __builtin_bit_cast(half8, hfr[kt * 64 + lane]);
            a0 = __builtin_amdgcn_mfma_f32_16x16x32_f16(__builtin_bit_cast(half8, frag[kt]), b, a0, 0, 0, 0);
            a1 = __builtin_amdgcn_mfma_f32_16x16x32_f16(__builtin_bit_cast(half8, frag[8 + kt]), b, a1, 0, 0, 0);
            a2 = __builtin_amdgcn_mfma_f32_16x16x32_f16(__builtin_bit_cast(half8, frag[16 + kt]), b, a2, 0, 0, 0);
            a3 = __builtin_amdgcn_mfma_f32_16x16x32_f16(__builtin_bit_cast(half8, frag[24 + kt]), b, a3, 0, 0, 0);
        }
        float* tr = tot + l16 * 772;
        *(f4*)&tr[mb] = a0;
        *(f4*)&tr[mb + 16] = a1;
        *(f4*)&tr[mb + 32] = a2;
        *(f4*)&tr[mb + 48] = a3;
        BAR_LDS();
        if (real) {
            const float* ts = tot + us * 772;
            float hcv[8];
            h2 px = __builtin_bit_cast(h2, hcp.x); h2 py = __builtin_bit_cast(h2, hcp.y);
            h2 pz = __builtin_bit_cast(h2, hcp.z); h2 pw = __builtin_bit_cast(h2, hcp.w);
            hcv[0] = (float)px.x; hcv[1] = (float)px.y; hcv[2] = (float)py.x; hcv[3] = (float)py.y;
            hcv[4] = (float)pz.x; hcv[5] = (float)pz.y; hcv[6] = (float)pw.x; hcv[7] = (float)pw.y;
#pragma unroll
            for (int hf = 0; hf < 2; ++hf) {
                int jb = j0 + hf * 4;
                float pf[4], pi_[4], pu[4];
                ubf4(praw[hf], pf);
                ubf4(praw[2 + hf], pi_);
                ubf4(praw[4 + hf], pu);
                f4 tf = *(const f4*)&ts[jb];
                f4 ti = *(const f4*)&ts[256 + jb];
                f4 tu = *(const f4*)&ts[512 + jb];
#pragma unroll
                for (int r = 0; r < 4; ++r) {
                    float ff = tf[r] + pf[r];
                    float ii = ti[r] + pi_[r];
                    float uu = tu[r] + pu[r];
                    hcv[hf * 4 + r] = tanh_(sigm(ii) * tanh_(uu) + sigm(ff) * hcv[hf * 4 + r]);
                }
            }
            hcp.x = pack_h2(hcv[0], hcv[1]); hcp.y = pack_h2(hcv[2], hcv[3]);
            hcp.z = pack_h2(hcv[4], hcv[5]); hcp.w = pack_h2(hcv[6], hcv[7]);
            hfr[hcell] = hcp;
        }
        BAR_LDS();
    }

    {
        const _Float16* base = Wihh + (w * 64 + l16) * HD;
#pragma unroll
        for (int t = 0; t < 4; ++t)
#pragma unroll
            for (int kt = 0; kt < 8; ++kt)
                frag[t * 8 + kt] = *(const uint4*)(base + t * 16 * HD + kt * 32 + quad * 8);
    }
    f4 a0 = (f4){0,0,0,0}, a1 = (f4){0,0,0,0}, a2 = (f4){0,0,0,0}, a3 = (f4){0,0,0,0};
#pragma unroll
    for (int kt = 0; kt < 8; ++kt) {
        half8 b = __builtin_bit_cast(half8, hfr[kt * 64 + lane]);
        a0 = __builtin_amdgcn_mfma_f32_16x16x32_f16(__builtin_bit_cast(half8, frag[kt]), b, a0, 0, 0, 0);
        a1 = __builtin_amdgcn_mfma_f32_16x16x32_f16(__builtin_bit_cast(half8, frag[8 + kt]), b, a1, 0, 0, 0);
        a2 = __builtin_amdgcn_mfma_f32_16x16x32_f16(__builtin_bit_cast(half8, frag[16 + kt]), b, a2, 0, 0, 0);
        a3 = __builtin_amdgcn_mfma_f32_16x16x32_f16(__builtin_bit_cast(half8, frag[24 + kt]), b, a3, 0, 0, 0);
    }
    if (l16 < NSB) {
        float* go = gi + (long)(s0 + l16) * TH;
        f4 b0 = *(const f4*)(bias2 + mb);
        f4 b1 = *(const f4*)(bias2 + mb + 16);
        f4 b2 = *(const f4*)(bias2 + mb + 32);
        f4 b3 = *(const f4*)(bias2 + mb + 48);
        *(f4*)(go + mb) = a0 + b0;
        *(f4*)(go + mb + 16) = a1 + b1;
        *(f4*)(go + mb + 32) = a2 + b2;
        *(f4*)(go + mb + 48) = a3 + b3;
    }
}

// ---------------- GRU v20: v17 single dispatch restored (split removed) ----------------
// r14: the 4-way split cost ~180us (4 x 202 = 808 vs unsplit 628; 3 extra weight-load +
// pipeline-prime prologues, per-quarter FETCH 1008KB confirms). The split was the
// decomposition instrument; phaseB/phaseC now fixed with real numbers -> merge back.
#define GB 8
__global__ void __launch_bounds__(512) k_gru(
                      const signed char* __restrict__ Wq, const float* __restrict__ rowscale,
                      const float* __restrict__ bhh,
                      const float* __restrict__ gi, const float* __restrict__ h0,
                      const float* __restrict__ tv,
                      const float* __restrict__ gateW, const float* __restrict__ gateU,
                      const float* __restrict__ gateb,
                      const float* __restrict__ outW, const float* __restrict__ outb,
                      float* __restrict__ out) {
    __shared__ __align__(16) signed char qbuf[2][HD]; // ping-pong h (i8, scale SH/127)
    __shared__ __align__(16) float gbuf[2][GB * TH];  // 48KB gi staging, double-buffered
    __shared__ float hts[HD];
    __shared__ float sgs[512];
    __shared__ float vvs[HD];
    __shared__ float lg[8];

    int tid = threadIdx.x;
    int lane = tid & 63, w = tid >> 6, quad = lane >> 4, l16 = lane & 15;

    // i8 fragments: r tiles rows w*32+c*16, z tiles 256+..., n tiles 512+... (v9 layout)
    i4 far_[2][4], faz[2][4], fan[2][4];
#pragma unroll
    for (int c = 0; c < 2; ++c) {
        const signed char* qr_ = Wq + (long)(w * 32 + c * 16 + l16) * HD;
        const signed char* qz_ = Wq + (long)(256 + w * 32 + c * 16 + l16) * HD;
        const signed char* qn_ = Wq + (long)(512 + w * 32 + c * 16 + l16) * HD;
#pragma unroll
        for (int kc = 0; kc < 4; ++kc) {
            far_[c][kc] = *(const i4*)(qr_ + kc * 64 + quad * 16);
            faz[c][kc] = *(const i4*)(qz_ + kc * 64 + quad * 16);
            fan[c][kc] = *(const i4*)(qn_ + kc * 64 + quad * 16);
        }
    }

    // per-lane ownership: h index j = w*32 + sc*16 + quad*4 + sr  (l16<8 unique)
    int sc = (l16 >> 2) & 1;
    int sr = l16 & 3;
    int j = w * 32 + sc * 16 + quad * 4 + sr;
    bool b2 = (sr & 2) != 0, b1 = (sr & 1) != 0, bc = (sc != 0);
    bool owner = (l16 < 8);

    float rs_r = rowscale[j];
    float rs_z = rowscale[256 + j];
    float rs_n = rowscale[512 + j];
    float bn_l = bhh[512 + j];

    float hv = h0[j];
    if (owner) {
        float hc = fminf(fmaxf(hv, -SH), SH);
        qbuf[0][j] = (signed char)(int)rintf(hc * (127.f / SH));
    }
    // stage gi block 0 directly; issue block 1 into registers
    float rg[12];
#pragma unroll
    for (int i = 0; i < 12; ++i) gbuf[0][i * 512 + tid] = gi[i * 512 + tid];
#pragma unroll
    for (int i = 0; i < 12; ++i) rg[i] = gi[GB * TH + i * 512 + tid];
    __syncthreads();

    for (int nb = 0; nb < NS / GB; ++nb) {
        int buf = nb & 1;
#pragma unroll
        for (int u = 0; u < GB; ++u) {
            if (u == 0) {
                // commit block nb+1 (in rg) to the other buffer; issue block nb+2
#pragma unroll
                for (int i = 0; i < 12; ++i) gbuf[buf ^ 1][i * 512 + tid] = rg[i];
                if (nb + 2 < NS / GB) {
                    const float* gsrc = gi + (long)(nb + 2) * GB * TH;
#pragma unroll
                    for (int i = 0; i < 12; ++i) rg[i] = gsrc[i * 512 + tid];
                }
            }
            const int p = u & 1;   // parity compile-time (GB even)
            const float* gl = &gbuf[buf][u * TH];
            float gr_l = gl[j], gz_l = gl[256 + j], gn_l = gl[512 + j];

            i4 qr[2], qz[2], qn[2];
#pragma unroll
            for (int c = 0; c < 2; ++c) { qr[c] = (i4){0,0,0,0}; qz[c] = (i4){0,0,0,0}; qn[c] = (i4){0,0,0,0}; }
#pragma unroll
            for (int kc = 0; kc < 4; ++kc) {
                i4 b = *(const i4*)&qbuf[p][kc * 64 + quad * 16];
                qr[0] = __builtin_amdgcn_mfma_i32_16x16x64_i8(far_[0][kc], b, qr[0], 0, 0, 0);
                qr[1] = __builtin_amdgcn_mfma_i32_16x16x64_i8(far_[1][kc], b, qr[1], 0, 0, 0);
                qz[0] = __builtin_amdgcn_mfma_i32_16x16x64_i8(faz[0][kc], b, qz[0], 0, 0, 0);
                qz[1] = __builtin_amdgcn_mfma_i32_16x16x64_i8(faz[1][kc], b, qz[1], 0, 0, 0);
                qn[0] = __builtin_amdgcn_mfma_i32_16x16x64_i8(fan[0][kc], b, qn[0], 0, 0, 0);
                qn[1] = __builtin_amdgcn_mfma_i32_16x16x64_i8(fan[1][kc], b, qn[1], 0, 0, 0);
            }
            // lane-select the (sc, sr) value from the 8 replicated D values
            int ra0 = bc ? qr[1][0] : qr[0][0], ra1 = bc ? qr[1][1] : qr[0][1];
            int ra2 = bc ? qr[1][2] : qr[0][2], ra3 = bc ? qr[1][3] : qr[0][3];
            int rt0 = b2 ? ra2 : ra0, rt1 = b2 ? ra3 : ra1;
            int qrv = b1 ? rt1 : rt0;
            int za0 = bc ? qz[1][0] : qz[0][0], za1 = bc ? qz[1][1] : qz[0][1];
            int za2 = bc ? qz[1][2] : qz[0][2], za3 = bc ? qz[1][3] : qz[0][3];
            int zt0 = b2 ? za2 : za0, zt1 = b2 ? za3 : za1;
            int qzv = b1 ? zt1 : zt0;
            int na0 = bc ? qn[1][0] : qn[0][0], na1 = bc ? qn[1][1] : qn[0][1];
            int na2 = bc ? qn[1][2] : qn[0][2], na3 = bc ? qn[1][3] : qn[0][3];
            int nt0 = b2 ? na2 : na0, nt1 = b2 ? na3 : na1;
            int qnv = b1 ? nt1 : nt0;
            // single gate update per lane
            float rv = sigm(gr_l + (float)qrv * rs_r);
            float zv = sigm(gz_l + (float)qzv * rs_z);
            float nv = tanh_(gn_l + rv * ((float)qnv * rs_n + bn_l));
            hv = (1.f - zv) * nv + zv * hv;
            if (owner) {
                float hc = fminf(fmaxf(hv, -SH), SH);
                qbuf[p ^ 1][j] = (signed char)(int)rintf(hc * (127.f / SH));
            }
            __syncthreads();
        }
    }

    // head
    if (owner) hts[j] = hv;
    __syncthreads();
    {
        float s = gateb[tid];
        for (int k = 0; k < HD; ++k)
            s += gateW[tid * HD + k] * hts[k] + gateU[tid * HD + k] * tv[k];
        sgs[tid] = sigm(s);
    }
    __syncthreads();
    if (tid < HD) vvs[tid] = tanh_(sgs[tid] * hts[tid] + sgs[256 + tid] * tv[tid]);
    __syncthreads();
    if (tid < 5) {
        float s = outb[tid];
        for (int k = 0; k < HD; ++k) s += outW[tid * HD + k] * vvs[k];
        lg[tid] = s;
    }
    __syncthreads();
    if (tid == 0) {
        float m = lg[0];
        for (int i = 1; i < 5; ++i) m = fmaxf(m, lg[i]);
        float e[5], sum = 0.f;
        for (int i = 0; i < 5; ++i) { e[i] = __expf(lg[i] - m); sum += e[i]; }
        for (int i = 0; i < 5; ++i) out[i] = e[i] / sum;
    }
}

extern "C" void kernel_launch(void* const* d_in, const int* in_sizes, int n_in,
                              void* d_out, int out_size, void* d_ws, size_t ws_size,
                              hipStream_t stream) {
    (void)in_sizes; (void)n_in; (void)out_size; (void)ws_size;
    const int* sIdx = (const int*)d_in[0];
    const int* depT = (const int*)d_in[1];
    const float* DT = (const float*)d_in[2];
    const float* h0 = (const float*)d_in[3];
    const float* emb = (const float*)d_in[4];
    const float* q = (const float*)d_in[5];
    const float* W = (const float*)d_in[6];
    const float* U = (const float*)d_in[7];
    const float* Dm = (const float*)d_in[8];
    const float* b = (const float*)d_in[9];
    const float* Wih = (const float*)d_in[10];
    const float* Whh = (const float*)d_in[11];
    const float* bih = (const float*)d_in[12];
    const float* bhh = (const float*)d_in[13];
    const float* gateW = (const float*)d_in[14];
    const float* gateU = (const float*)d_in[15];
    const float* gateb = (const float*)d_in[16];
    const float* mlpW = (const float*)d_in[17];
    const float* mlpb = (const float*)d_in[18];
    const float* outW = (const float*)d_in[19];
    const float* outb = (const float*)d_in[20];

    char* ws = (char*)d_ws;
    unsigned short* Wb = (unsigned short*)ws;   ws += 768 * 320 * 2;
    _Float16* Uh = (_Float16*)ws;               ws += 768 * 256 * 2;
    _Float16* Wihh = (_Float16*)ws;             ws += 768 * 256 * 2;
    signed char* Wq = (signed char*)ws;         ws += 768 * 256;
    float* rowscale = (float*)ws;               ws += 768 * 4;
    float* bias2 = (float*)ws;                  ws += 768 * 4;
    float* Dq = (float*)ws;                     ws += 10 * 768 * 4;
    float* tv = (float*)ws;                     ws += 1024;
    ws = (char*)d_ws + ((((size_t)(ws - (char*)d_ws)) + 4095) & ~(size_t)4095);
    unsigned short* pre = (unsigned short*)ws;  ws += (size_t)65536 * 768 * 2;
    float* gi = (float*)ws;                     ws += (size_t)1024 * 768 * 4;

    k_prep<<<dim3(799), dim3(256), 0, stream>>>(W, U, Wih, Whh, q, Dm, DT, mlpW, mlpb,
                                                bih, bhh,
                                                Wb, Uh, Wihh, Wq, rowscale, bias2, Dq, tv);
    k_phaseB<<<dim3(2048), dim3(256), 0, stream>>>(sIdx, depT, emb, Wb, Dq, b, pre);
    k_phaseC<<<dim3(256), dim3(768), 0, stream>>>(pre, Uh, Wihh, bias2, gi);
    k_gru<<<dim3(1), dim3(512), 0, stream>>>(Wq, rowscale, bhh, gi, h0, tv,
                                             gateW, gateU, gateb, outW, outb, (float*)d_out);
}

// Round 16
// 1102.062 us; speedup vs baseline: 1.1178x; 1.0009x over previous
//
#include <hip/hip_runtime.h>

typedef short short8 __attribute__((ext_vector_type(8)));
typedef float f4 __attribute__((ext_vector_type(4)));
typedef int i4 __attribute__((ext_vector_type(4)));
typedef _Float16 half8 __attribute__((ext_vector_type(8)));
typedef _Float16 h2 __attribute__((ext_vector_type(2)));

#define HD 256
#define ED 300
#define EP 320
#define TH 768
#define NS 1024
#define LW 64
#define SH 4.5f

#define BAR_LDS() do { asm volatile("s_waitcnt lgkmcnt(0)" ::: "memory"); \
                       __builtin_amdgcn_s_barrier(); } while (0)

__device__ __forceinline__ unsigned short f2bf(float f) {
    unsigned int u = __float_as_uint(f);
    u = (u + 0x7FFFu + ((u >> 16) & 1u)) >> 16;
    return (unsigned short)u;
}
__device__ __forceinline__ float bf2f(unsigned short s) {
    return __uint_as_float(((unsigned int)s) << 16);
}
__device__ __forceinline__ float sigm(float x) {
    return __builtin_amdgcn_rcpf(1.f + __expf(-x));
}
__device__ __forceinline__ float tanh_(float x) {
    x = fminf(fmaxf(x, -15.f), 15.f);
    return 1.f - 2.f * __builtin_amdgcn_rcpf(1.f + __expf(2.f * x));
}
__device__ __forceinline__ unsigned int pack_h2(float a, float b) {
    h2 p; p.x = (_Float16)a; p.y = (_Float16)b;
    return __builtin_bit_cast(unsigned int, p);
}

__device__ __forceinline__ void load8bf(const unsigned short* p, float* o) {
    uint4 a = *(const uint4*)p;
    o[0] = bf2f((unsigned short)(a.x & 0xffff)); o[1] = bf2f((unsigned short)(a.x >> 16));
    o[2] = bf2f((unsigned short)(a.y & 0xffff)); o[3] = bf2f((unsigned short)(a.y >> 16));
    o[4] = bf2f((unsigned short)(a.z & 0xffff)); o[5] = bf2f((unsigned short)(a.z >> 16));
    o[6] = bf2f((unsigned short)(a.w & 0xffff)); o[7] = bf2f((unsigned short)(a.w >> 16));
}
__device__ __forceinline__ void ubf4(uint2 a, float* o) {
    o[0] = bf2f((unsigned short)(a.x & 0xffff)); o[1] = bf2f((unsigned short)(a.x >> 16));
    o[2] = bf2f((unsigned short)(a.y & 0xffff)); o[3] = bf2f((unsigned short)(a.y >> 16));
}

// ---------------- prep: weight conversions, i8 quantization (ALL 768 Whh rows), Dq, topic ----------------
__global__ void k_prep(const float* __restrict__ W, const float* __restrict__ U,
                       const float* __restrict__ Wih, const float* __restrict__ Whh,
                       const float* __restrict__ q, const float* __restrict__ Dm,
                       const float* __restrict__ DT, const float* __restrict__ mlpW,
                       const float* __restrict__ mlpb,
                       const float* __restrict__ bih, const float* __restrict__ bhh,
                       unsigned short* __restrict__ Wb, _Float16* __restrict__ Uh,
                       _Float16* __restrict__ Wihh,
                       signed char* __restrict__ Wq, float* __restrict__ rowscale,
                       float* __restrict__ bias2,
                       float* __restrict__ Dq, float* __restrict__ tv) {
    __shared__ float smax[4];
    int bid = blockIdx.x, tid = threadIdx.x;
    if (bid < 768) {
        int r = bid;
        for (int j = tid; j < EP; j += 256)
            Wb[r * EP + j] = (j < ED) ? f2bf(W[r * ED + j]) : (unsigned short)0;
        float whv = Whh[r * HD + tid];
        for (int j = tid; j < HD; j += 256) {
            Uh[r * HD + j] = (_Float16)U[r * HD + j];
            Wihh[r * HD + j] = (_Float16)Wih[r * HD + j];
        }
        // per-row i8 quantization of ALL Whh rows
        float v = fabsf(whv);
        for (int o = 32; o; o >>= 1) v = fmaxf(v, __shfl_xor(v, o));
        if ((tid & 63) == 0) smax[tid >> 6] = v;
        __syncthreads();
        float am = fmaxf(fmaxf(smax[0], smax[1]), fmaxf(smax[2], smax[3]));
        float inv = (am > 0.f) ? 127.f / am : 0.f;
        int qi = (int)rintf(whv * inv);
        qi = max(-127, min(127, qi));
        Wq[r * HD + tid] = (signed char)qi;
        if (tid == 0) rowscale[r] = (am / 127.f) * (SH / 127.f);
    } else if (bid < 798) {
        int idx = bid - 768;
        int d = idx / 3, part = idx - d * 3;
        int n = part * 256 + tid;
        float s = 0.f;
        for (int h = 0; h < HD; ++h) s += Dm[n * HD + h] * q[d * HD + h];
        Dq[d * TH + n] = s;
    } else {
        if (tid < HD) {
            float s = 0.f;
            for (int k = 0; k < 100; ++k) s += mlpW[tid * 100 + k] * DT[k];
            tv[tid] = tanh_(s + mlpb[tid]);
        }
        for (int r = tid; r < TH; r += 256)
            bias2[r] = bih[r] + ((r < 512) ? bhh[r] : 0.f);
    }
}

// ---------------- phase B v7: N-split 2-way (384 cols/block), 5 blocks/CU ----------------
// r15: phaseB is ~90% stall (traffic 145MB -> 23us floor, measured 201us; VALUBusy 7%,
// Occ 29%). Latency/occupancy prescription: split N -> acc[2][6] (48 VGPR), per-block Wb
// stream halves (240KB), (256,5) -> 5 blocks/CU = 67% more resident waves. Gather
// duplicated per pair (+78MB issued, L3-absorbed). Numerics: pure column partition,
// bit-identical. Guard: WRITE must stay ~98MB (no spill); VGPR ~90-102.
#define XP 328
__launch_bounds__(256, 5)
__global__ void k_phaseB(const int* __restrict__ sIdx, const int* __restrict__ depT,
                         const float* __restrict__ emb, const unsigned short* __restrict__ Wb,
                         const float* __restrict__ Dq, const float* __restrict__ bias,
                         unsigned short* __restrict__ pre) {
    __shared__ __align__(16) unsigned short sbuf[32 * XP]; // 20992B; tbuf needs 12544B
    unsigned short* xbf = sbuf;
    unsigned short* tbuf = sbuf;
    int tid = threadIdx.x;
    int nhalf = blockIdx.x & 1;          // which 384-col half of the 768 outputs
    int c0 = (blockIdx.x >> 1) * 32;     // which 32 words

    // stage 32 gathered x rows as bf16 (float4 loads; emb rows are 1200B = 75x16B aligned)
    for (int i = tid; i < 32 * 80; i += 256) {
        int row = i / 80, c4 = i - row * 80;
        unsigned int lo = 0, hi = 0;
        if (c4 < 75) {
            int idx = sIdx[c0 + row];
            float4 v = *(const float4*)(emb + (long)idx * ED + c4 * 4);
            lo = (unsigned int)f2bf(v.x) | ((unsigned int)f2bf(v.y) << 16);
            hi = (unsigned int)f2bf(v.z) | ((unsigned int)f2bf(v.w) << 16);
        }
        uint2 pv; pv.x = lo; pv.y = hi;
        *(uint2*)&xbf[row * XP + c4 * 4] = pv;
    }
    __syncthreads();

    int lane = tid & 63;
    int w = tid >> 6;
    int quad = lane >> 4, l16 = lane & 15;

    f4 acc[2][6];
#pragma unroll
    for (int cs = 0; cs < 2; ++cs)
#pragma unroll
        for (int ms = 0; ms < 6; ++ms) acc[cs][ms] = (f4){0.f, 0.f, 0.f, 0.f};

    const unsigned short* wbase = Wb + (nhalf * 384 + w * 96 + l16) * EP;

#pragma unroll
    for (int kt = 0; kt < 10; ++kt) {
        int k0 = kt * 32 + quad * 8;
        short8 bf0 = *(const short8*)&xbf[l16 * XP + k0];
        short8 bf1 = *(const short8*)&xbf[(16 + l16) * XP + k0];
#pragma unroll
        for (int ms = 0; ms < 6; ++ms) {
            short8 af = *(const short8*)(wbase + ms * 16 * EP + k0);
            acc[0][ms] = __builtin_amdgcn_mfma_f32_16x16x32_bf16(af, bf0, acc[0][ms], 0, 0, 0);
            acc[1][ms] = __builtin_amdgcn_mfma_f32_16x16x32_bf16(af, bf1, acc[1][ms], 0, 0, 0);
        }
    }
    __syncthreads();   // xbf dead from here; sbuf becomes tbuf (16 x 392 shorts)

#pragma unroll
    for (int cs = 0; cs < 2; ++cs) {
        int xr = c0 + cs * 16 + l16;
        int l = xr & 63, s = xr >> 6;
        int dep = (l == 63) ? 9 : depT[s * 63 + l];
        const float* dqrow = Dq + dep * TH;
#pragma unroll
        for (int ms = 0; ms < 6; ++ms) {
            int lc = w * 96 + ms * 16 + quad * 4;          // local col within the half
            int ncol = nhalf * 384 + lc;
            f4 dq4 = *(const f4*)&dqrow[ncol];    // L2-resident (30KB table)
            f4 b4 = *(const f4*)&bias[ncol];
            unsigned int lo = (unsigned int)f2bf(acc[cs][ms][0] + dq4[0] + b4[0]) |
                              ((unsigned int)f2bf(acc[cs][ms][1] + dq4[1] + b4[1]) << 16);
            unsigned int hi = (unsigned int)f2bf(acc[cs][ms][2] + dq4[2] + b4[2]) |
                              ((unsigned int)f2bf(acc[cs][ms][3] + dq4[3] + b4[3]) << 16);
            uint2 v; v.x = lo; v.y = hi;
            *(uint2*)&tbuf[l16 * 392 + lc] = v;
        }
        __syncthreads();
        // coalesced row-major store: 16 rows x 48 uint4 chunks = 768 / 256 thr = 3 iters
        for (int it = 0; it < 3; ++it) {
            int flat = it * 256 + tid;
            int row = flat / 48;
            int ch = flat - row * 48;
            uint4 v = *(const uint4*)&tbuf[row * 392 + ch * 8];
            *(uint4*)(pre + (long)(c0 + cs * 16 + row) * TH + nhalf * 384 + ch * 8) = v;
        }
        __syncthreads();
    }
}

// ---------------- phase C v2: 4 sentences/block x 256 blocks (full-chip), raw LDS barriers ----------------
#define NSB 4
__global__ void __launch_bounds__(768) k_phaseC(
                         const unsigned short* __restrict__ pre,
                         const _Float16* __restrict__ Uh,
                         const _Float16* __restrict__ Wihh,
                         const float* __restrict__ bias2,
                         float* __restrict__ gi) {
    __shared__ __align__(16) uint4 hfr[512];
    __shared__ __align__(16) float tot[16 * 772];
    int tid = threadIdx.x;
    int lane = tid & 63, w = tid >> 6, quad = lane >> 4, l16 = lane & 15;
    int s0 = blockIdx.x * NSB;

    uint4 frag[32];
    {
        const _Float16* base = Uh + (w * 64 + l16) * HD;
#pragma unroll
        for (int t = 0; t < 4; ++t)
#pragma unroll
            for (int kt = 0; kt < 8; ++kt)
                frag[t * 8 + kt] = *(const uint4*)(base + t * 16 * HD + kt * 32 + quad * 8);
    }

    int us = tid >> 5;
    int jg = tid & 31;
    int j0 = jg * 8;
    int hcell = (j0 >> 5) * 64 + 16 * ((j0 >> 3) & 3) + us;
    uint4 hcp;
    bool act = (tid < 512);
    bool real = act && (us < NSB);

    if (act) {
        if (real) {
            const unsigned short* prow = pre + ((long)(s0 + us) * LW + 63) * TH;
            float iv[8], uv[8], hcv[8];
            load8bf(prow + 256 + j0, iv);
            load8bf(prow + 512 + j0, uv);
#pragma unroll
            for (int r = 0; r < 8; ++r) hcv[r] = tanh_(sigm(iv[r]) * tanh_(uv[r]));
            hcp.x = pack_h2(hcv[0], hcv[1]); hcp.y = pack_h2(hcv[2], hcv[3]);
            hcp.z = pack_h2(hcv[4], hcv[5]); hcp.w = pack_h2(hcv[6], hcv[7]);
        } else {
            hcp.x = 0u; hcp.y = 0u; hcp.z = 0u; hcp.w = 0u;  // zero-pad cols NSB..15
        }
        hfr[hcell] = hcp;
    }
    __syncthreads();

    int mb = w * 64 + quad * 4;

    for (int step = 0; step < 63; ++step) {
        int l = 62 - step;
        uint2 praw[6];
        if (real) {
            const unsigned short* prow = pre + ((long)(s0 + us) * LW + l) * TH;
#pragma unroll
            for (int g = 0; g < 3; ++g) {
                praw[2 * g]     = *(const uint2*)(prow + g * 256 + j0);
                praw[2 * g + 1] = *(const uint2*)(prow + g * 256 + j0 + 4);
            }
        }
        f4 a0 = (f4){0,0,0,0}, a1 = (f4){0,0,0,0}, a2 = (f4){0,0,0,0}, a3 = (f4){0,0,0,0};
#pragma unroll
        for (int kt = 0; kt < 8; ++kt) {
            half8 b = __builtin_bit_cast(half8, hfr[kt * 64 + lane]);
            a0 = __builtin_amdgcn_mfma_f32_16x16x32_f16(__builtin_bit_cast(half8, frag[kt]), b, a0, 0, 0, 0);
            a1 = __builtin_amdgcn_mfma_f32_16x16x32_f16(__builtin_bit_cast(half8, frag[8 + kt]), b, a1, 0, 0, 0);
            a2 = __builtin_amdgcn_mfma_f32_16x16x32_f16(__builtin_bit_cast(half8, frag[16 + kt]), b, a2, 0, 0, 0);
            a3 = __builtin_amdgcn_mfma_f32_16x16x32_f16(__builtin_bit_cast(half8, frag[24 + kt]), b, a3, 0, 0, 0);
        }
        float* tr = tot + l16 * 772;
        *(f4*)&tr[mb] = a0;
        *(f4*)&tr[mb + 16] = a1;
        *(f4*)&tr[mb + 32] = a2;
        *(f4*)&tr[mb + 48] = a3;
        BAR_LDS();
        if (real) {
            const float* ts = tot + us * 772;
            float hcv[8];
            h2 px = __builtin_bit_cast(h2, hcp.x); h2 py = __builtin_bit_cast(h2, hcp.y);
            h2 pz = __builtin_bit_cast(h2, hcp.z); h2 pw = __builtin_bit_cast(h2, hcp.w);
            hcv[0] = (float)px.x; hcv[1] = (float)px.y; hcv[2] = (float)py.x; hcv[3] = (float)py.y;
            hcv[4] = (float)pz.x; hcv[5] = (float)pz.y; hcv[6] = (float)pw.x; hcv[7] = (float)pw.y;
#pragma unroll
            for (int hf = 0; hf < 2; ++hf) {
                int jb = j0 + hf * 4;
                float pf[4], pi_[4], pu[4];
                ubf4(praw[hf], pf);
                ubf4(praw[2 + hf], pi_);
                ubf4(praw[4 + hf], pu);
                f4 tf = *(const f4*)&ts[jb];
                f4 ti = *(const f4*)&ts[256 + jb];
                f4 tu = *(const f4*)&ts[512 + jb];
#pragma unroll
                for (int r = 0; r < 4; ++r) {
                    float ff = tf[r] + pf[r];
                    float ii = ti[r] + pi_[r];
                    float uu = tu[r] + pu[r];
                    hcv[hf * 4 + r] = tanh_(sigm(ii) * tanh_(uu) + sigm(ff) * hcv[hf * 4 + r]);
                }
            }
            hcp.x = pack_h2(hcv[0], hcv[1]); hcp.y = pack_h2(hcv[2], hcv[3]);
            hcp.z = pack_h2(hcv[4], hcv[5]); hcp.w = pack_h2(hcv[6], hcv[7]);
            hfr[hcell] = hcp;
        }
        BAR_LDS();
    }

    {
        const _Float16* base = Wihh + (w * 64 + l16) * HD;
#pragma unroll
        for (int t = 0; t < 4; ++t)
#pragma unroll
            for (int kt = 0; kt < 8; ++kt)
                frag[t * 8 + kt] = *(const uint4*)(base + t * 16 * HD + kt * 32 + quad * 8);
    }
    f4 a0 = (f4){0,0,0,0}, a1 = (f4){0,0,0,0}, a2 = (f4){0,0,0,0}, a3 = (f4){0,0,0,0};
#pragma unroll
    for (int kt = 0; kt < 8; ++kt) {
        half8 b = __builtin_bit_cast(half8, hfr[kt * 64 + lane]);
        a0 = __builtin_amdgcn_mfma_f32_16x16x32_f16(__builtin_bit_cast(half8, frag[kt]), b, a0, 0, 0, 0);
        a1 = __builtin_amdgcn_mfma_f32_16x16x32_f16(__builtin_bit_cast(half8, frag[8 + kt]), b, a1, 0, 0, 0);
        a2 = __builtin_amdgcn_mfma_f32_16x16x32_f16(__builtin_bit_cast(half8, frag[16 + kt]), b, a2, 0, 0, 0);
        a3 = __builtin_amdgcn_mfma_f32_16x16x32_f16(__builtin_bit_cast(half8, frag[24 + kt]), b, a3, 0, 0, 0);
    }
    if (l16 < NSB) {
        float* go = gi + (long)(s0 + l16) * TH;
        f4 b0 = *(const f4*)(bias2 + mb);
        f4 b1 = *(const f4*)(bias2 + mb + 16);
        f4 b2 = *(const f4*)(bias2 + mb + 32);
        f4 b3 = *(const f4*)(bias2 + mb + 48);
        *(f4*)(go + mb) = a0 + b0;
        *(f4*)(go + mb + 16) = a1 + b1;
        *(f4*)(go + mb + 32) = a2 + b2;
        *(f4*)(go + mb + 48) = a3 + b3;
    }
}

// ---------------- GRU v20: v17 single dispatch (best measured: 628us) ----------------
#define GB 8
__global__ void __launch_bounds__(512) k_gru(
                      const signed char* __restrict__ Wq, const float* __restrict__ rowscale,
                      const float* __restrict__ bhh,
                      const float* __restrict__ gi, const float* __restrict__ h0,
                      const float* __restrict__ tv,
                      const float* __restrict__ gateW, const float* __restrict__ gateU,
                      const float* __restrict__ gateb,
                      const float* __restrict__ outW, const float* __restrict__ outb,
                      float* __restrict__ out) {
    __shared__ __align__(16) signed char qbuf[2][HD]; // ping-pong h (i8, scale SH/127)
    __shared__ __align__(16) float gbuf[2][GB * TH];  // 48KB gi staging, double-buffered
    __shared__ float hts[HD];
    __shared__ float sgs[512];
    __shared__ float vvs[HD];
    __shared__ float lg[8];

    int tid = threadIdx.x;
    int lane = tid & 63, w = tid >> 6, quad = lane >> 4, l16 = lane & 15;

    // i8 fragments: r tiles rows w*32+c*16, z tiles 256+..., n tiles 512+... (v9 layout)
    i4 far_[2][4], faz[2][4], fan[2][4];
#pragma unroll
    for (int c = 0; c < 2; ++c) {
        const signed char* qr_ = Wq + (long)(w * 32 + c * 16 + l16) * HD;
        const signed char* qz_ = Wq + (long)(256 + w * 32 + c * 16 + l16) * HD;
        const signed char* qn_ = Wq + (long)(512 + w * 32 + c * 16 + l16) * HD;
#pragma unroll
        for (int kc = 0; kc < 4; ++kc) {
            far_[c][kc] = *(const i4*)(qr_ + kc * 64 + quad * 16);
            faz[c][kc] = *(const i4*)(qz_ + kc * 64 + quad * 16);
            fan[c][kc] = *(const i4*)(qn_ + kc * 64 + quad * 16);
        }
    }

    // per-lane ownership: h index j = w*32 + sc*16 + quad*4 + sr  (l16<8 unique)
    int sc = (l16 >> 2) & 1;
    int sr = l16 & 3;
    int j = w * 32 + sc * 16 + quad * 4 + sr;
    bool b2 = (sr & 2) != 0, b1 = (sr & 1) != 0, bc = (sc != 0);
    bool owner = (l16 < 8);

    float rs_r = rowscale[j];
    float rs_z = rowscale[256 + j];
    float rs_n = rowscale[512 + j];
    float bn_l = bhh[512 + j];

    float hv = h0[j];
    if (owner) {
        float hc = fminf(fmaxf(hv, -SH), SH);
        qbuf[0][j] = (signed char)(int)rintf(hc * (127.f / SH));
    }
    // stage gi block 0 directly; issue block 1 into registers
    float rg[12];
#pragma unroll
    for (int i = 0; i < 12; ++i) gbuf[0][i * 512 + tid] = gi[i * 512 + tid];
#pragma unroll
    for (int i = 0; i < 12; ++i) rg[i] = gi[GB * TH + i * 512 + tid];
    __syncthreads();

    for (int nb = 0; nb < NS / GB; ++nb) {
        int buf = nb & 1;
#pragma unroll
        for (int u = 0; u < GB; ++u) {
            if (u == 0) {
                // commit block nb+1 (in rg) to the other buffer; issue block nb+2
#pragma unroll
                for (int i = 0; i < 12; ++i) gbuf[buf ^ 1][i * 512 + tid] = rg[i];
                if (nb + 2 < NS / GB) {
                    const float* gsrc = gi + (long)(nb + 2) * GB * TH;
#pragma unroll
                    for (int i = 0; i < 12; ++i) rg[i] = gsrc[i * 512 + tid];
                }
            }
            const int p = u & 1;   // parity compile-time (GB even)
            const float* gl = &gbuf[buf][u * TH];
            float gr_l = gl[j], gz_l = gl[256 + j], gn_l = gl[512 + j];

            i4 qr[2], qz[2], qn[2];
#pragma unroll
            for (int c = 0; c < 2; ++c) { qr[c] = (i4){0,0,0,0}; qz[c] = (i4){0,0,0,0}; qn[c] = (i4){0,0,0,0}; }
#pragma unroll
            for (int kc = 0; kc < 4; ++kc) {
                i4 b = *(const i4*)&qbuf[p][kc * 64 + quad * 16];
                qr[0] = __builtin_amdgcn_mfma_i32_16x16x64_i8(far_[0][kc], b, qr[0], 0, 0, 0);
                qr[1] = __builtin_amdgcn_mfma_i32_16x16x64_i8(far_[1][kc], b, qr[1], 0, 0, 0);
                qz[0] = __builtin_amdgcn_mfma_i32_16x16x64_i8(faz[0][kc], b, qz[0], 0, 0, 0);
                qz[1] = __builtin_amdgcn_mfma_i32_16x16x64_i8(faz[1][kc], b, qz[1], 0, 0, 0);
                qn[0] = __builtin_amdgcn_mfma_i32_16x16x64_i8(fan[0][kc], b, qn[0], 0, 0, 0);
                qn[1] = __builtin_amdgcn_mfma_i32_16x16x64_i8(fan[1][kc], b, qn[1], 0, 0, 0);
            }
            // lane-select the (sc, sr) value from the 8 replicated D values
            int ra0 = bc ? qr[1][0] : qr[0][0], ra1 = bc ? qr[1][1] : qr[0][1];
            int ra2 = bc ? qr[1][2] : qr[0][2], ra3 = bc ? qr[1][3] : qr[0][3];
            int rt0 = b2 ? ra2 : ra0, rt1 = b2 ? ra3 : ra1;
            int qrv = b1 ? rt1 : rt0;
            int za0 = bc ? qz[1][0] : qz[0][0], za1 = bc ? qz[1][1] : qz[0][1];
            int za2 = bc ? qz[1][2] : qz[0][2], za3 = bc ? qz[1][3] : qz[0][3];
            int zt0 = b2 ? za2 : za0, zt1 = b2 ? za3 : za1;
            int qzv = b1 ? zt1 : zt0;
            int na0 = bc ? qn[1][0] : qn[0][0], na1 = bc ? qn[1][1] : qn[0][1];
            int na2 = bc ? qn[1][2] : qn[0][2], na3 = bc ? qn[1][3] : qn[0][3];
            int nt0 = b2 ? na2 : na0, nt1 = b2 ? na3 : na1;
            int qnv = b1 ? nt1 : nt0;
            // single gate update per lane
            float rv = sigm(gr_l + (float)qrv * rs_r);
            float zv = sigm(gz_l + (float)qzv * rs_z);
            float nv = tanh_(gn_l + rv * ((float)qnv * rs_n + bn_l));
            hv = (1.f - zv) * nv + zv * hv;
            if (owner) {
                float hc = fminf(fmaxf(hv, -SH), SH);
                qbuf[p ^ 1][j] = (signed char)(int)rintf(hc * (127.f / SH));
            }
            __syncthreads();
        }
    }

    // head
    if (owner) hts[j] = hv;
    __syncthreads();
    {
        float s = gateb[tid];
        for (int k = 0; k < HD; ++k)
            s += gateW[tid * HD + k] * hts[k] + gateU[tid * HD + k] * tv[k];
        sgs[tid] = sigm(s);
    }
    __syncthreads();
    if (tid < HD) vvs[tid] = tanh_(sgs[tid] * hts[tid] + sgs[256 + tid] * tv[tid]);
    __syncthreads();
    if (tid < 5) {
        float s = outb[tid];
        for (int k = 0; k < HD; ++k) s += outW[tid * HD + k] * vvs[k];
        lg[tid] = s;
    }
    __syncthreads();
    if (tid == 0) {
        float m = lg[0];
        for (int i = 1; i < 5; ++i) m = fmaxf(m, lg[i]);
        float e[5], sum = 0.f;
        for (int i = 0; i < 5; ++i) { e[i] = __expf(lg[i] - m); sum += e[i]; }
        for (int i = 0; i < 5; ++i) out[i] = e[i] / sum;
    }
}

extern "C" void kernel_launch(void* const* d_in, const int* in_sizes, int n_in,
                              void* d_out, int out_size, void* d_ws, size_t ws_size,
                              hipStream_t stream) {
    (void)in_sizes; (void)n_in; (void)out_size; (void)ws_size;
    const int* sIdx = (const int*)d_in[0];
    const int* depT = (const int*)d_in[1];
    const float* DT = (const float*)d_in[2];
    const float* h0 = (const float*)d_in[3];
    const float* emb = (const float*)d_in[4];
    const float* q = (const float*)d_in[5];
    const float* W = (const float*)d_in[6];
    const float* U = (const float*)d_in[7];
    const float* Dm = (const float*)d_in[8];
    const float* b = (const float*)d_in[9];
    const float* Wih = (const float*)d_in[10];
    const float* Whh = (const float*)d_in[11];
    const float* bih = (const float*)d_in[12];
    const float* bhh = (const float*)d_in[13];
    const float* gateW = (const float*)d_in[14];
    const float* gateU = (const float*)d_in[15];
    const float* gateb = (const float*)d_in[16];
    const float* mlpW = (const float*)d_in[17];
    const float* mlpb = (const float*)d_in[18];
    const float* outW = (const float*)d_in[19];
    const float* outb = (const float*)d_in[20];

    char* ws = (char*)d_ws;
    unsigned short* Wb = (unsigned short*)ws;   ws += 768 * 320 * 2;
    _Float16* Uh = (_Float16*)ws;               ws += 768 * 256 * 2;
    _Float16* Wihh = (_Float16*)ws;             ws += 768 * 256 * 2;
    signed char* Wq = (signed char*)ws;         ws += 768 * 256;
    float* rowscale = (float*)ws;               ws += 768 * 4;
    float* bias2 = (float*)ws;                  ws += 768 * 4;
    float* Dq = (float*)ws;                     ws += 10 * 768 * 4;
    float* tv = (float*)ws;                     ws += 1024;
    ws = (char*)d_ws + ((((size_t)(ws - (char*)d_ws)) + 4095) & ~(size_t)4095);
    unsigned short* pre = (unsigned short*)ws;  ws += (size_t)65536 * 768 * 2;
    float* gi = (float*)ws;                     ws += (size_t)1024 * 768 * 4;

    k_prep<<<dim3(799), dim3(256), 0, stream>>>(W, U, Wih, Whh, q, Dm, DT, mlpW, mlpb,
                                                bih, bhh,
                                                Wb, Uh, Wihh, Wq, rowscale, bias2, Dq, tv);
    k_phaseB<<<dim3(4096), dim3(256), 0, stream>>>(sIdx, depT, emb, Wb, Dq, b, pre);
    k_phaseC<<<dim3(256), dim3(768), 0, stream>>>(pre, Uh, Wihh, bias2, gi);
    k_gru<<<dim3(1), dim3(512), 0, stream>>>(Wq, rowscale, bhh, gi, h0, tv,
                                             gateW, gateU, gateb, outW, outb, (float*)d_out);
}